// Round 15
// baseline (333.481 us; speedup 1.0000x reference)
//
#include <hip/hip_runtime.h>
#include <hip/hip_bf16.h>
#include <math.h>

typedef __hip_bfloat16 bf16;
typedef __attribute__((ext_vector_type(8))) short short8;
typedef __attribute__((ext_vector_type(4))) float f32x4;

#define BB 8
#define LL 2048
#define DD 512
#define FF 1025   // LL/2+1
#define GP 1088   // g padded to 17*64 for ctx BK=64 K-chunks
#define FPAD 1152 // freq rows padded per (plane,b): 9 tiles of 128
#define PSTRIDE 589824   // pb panel-block stride = 64*FPAD*8 elements
#define ATT_SCALE 0.04419417382415922f   // 512^-0.5

__device__ __forceinline__ float b2f(bf16 v) { return __bfloat162float(v); }
__device__ __forceinline__ bf16  f2b(float v) { return __float2bfloat16(v); }
__device__ __forceinline__ float s2f(short s) { bf16 t; *reinterpret_cast<short*>(&t) = s; return b2f(t); }
__device__ __forceinline__ unsigned pk2f(float a, float b) {
    bf16 ha = f2b(a), hb = f2b(b);
    return (unsigned)*(unsigned short*)&ha | ((unsigned)*(unsigned short*)&hb << 16);
}

#define MFMA16(a, b, c) __builtin_amdgcn_mfma_f32_16x16x32_bf16((a), (b), (c), 0, 0, 0)

// exact bf16 negation of an 8-element fragment (sign-bit flip)
__device__ __forceinline__ short8 neg8(short8 v) {
    short8 r;
    #pragma unroll
    for (int t = 0; t < 8; ++t) r[t] = (short)(v[t] ^ (short)0x8000);
    return r;
}

// async global->LDS: 16B per lane, dest = wave-uniform base + lane*16 (linear)
typedef __attribute__((address_space(1))) const unsigned int gu32;
typedef __attribute__((address_space(3))) unsigned int lu32;
__device__ __forceinline__ void gl16(const void* g, void* l) {
    __builtin_amdgcn_global_load_lds((gu32*)g, (lu32*)l, 16, 0, 0);
}

template<bool F32>
__device__ __forceinline__ float ldin(const void* p, size_t i) {
    if (F32) return ((const float*)p)[i];
    else     return b2f(((const bf16*)p)[i]);
}

// ---------------------------------------------------------------------------
// dtype detector (flag: 1 = fp32 inputs, 0 = bf16).
// ---------------------------------------------------------------------------
__global__ __launch_bounds__(256) void detect_dtype(const unsigned short* __restrict__ x,
                                                    int* __restrict__ flag)
{
    __shared__ int cnt[256];
    int c = 0;
    for (int i = threadIdx.x; i < 4096; i += 256) {
        const int e = (x[i] >> 7) & 0xFF;
        c += (e >= 100 && e <= 150) ? 1 : 0;
    }
    cnt[threadIdx.x] = c;
    __syncthreads();
    for (int s = 128; s; s >>= 1) {
        if (threadIdx.x < s) cnt[threadIdx.x] += cnt[threadIdx.x + s];
        __syncthreads();
    }
    if (threadIdx.x == 0) *flag = (cnt[0] < 3400) ? 1 : 0;
}

// ---------------------------------------------------------------------------
// split_w_t (+ fused bias prep): W[512,512] -> transposed bf16 plane WT[n][k];
// block (0,0,z) also writes bias_f[z*512..]. Saves the prep_bias dispatch.
// ---------------------------------------------------------------------------
__global__ __launch_bounds__(256) void split_w_t(const void* __restrict__ W0,
                                                 const void* __restrict__ W1,
                                                 const void* __restrict__ W2,
                                                 const void* __restrict__ W3,
                                                 const void* __restrict__ b0,
                                                 const void* __restrict__ b1,
                                                 const void* __restrict__ b2,
                                                 const void* __restrict__ b3,
                                                 bf16* __restrict__ WT,
                                                 float* __restrict__ bias_f,
                                                 const int* __restrict__ flag)
{
    const int z = blockIdx.z;
    const void* W = z == 0 ? W0 : (z == 1 ? W1 : (z == 2 ? W2 : W3));
    bf16* Wh = WT + (size_t)z * 524288;
    const int k0 = blockIdx.x * 32, n0 = blockIdx.y * 32;
    const bool f32 = (*flag) != 0;
    __shared__ float Tl[32][33];
    for (int it = 0; it < 4; ++it) {
        const int idx = it * 256 + threadIdx.x;
        const int lk = idx >> 5, ln = idx & 31;
        Tl[lk][ln] = f32 ? ldin<true>(W, (size_t)(k0 + lk) * 512 + n0 + ln)
                         : ldin<false>(W, (size_t)(k0 + lk) * 512 + n0 + ln);
    }
    __syncthreads();
    for (int it = 0; it < 4; ++it) {
        const int idx = it * 256 + threadIdx.x;
        const int ln = idx >> 5, lk = idx & 31;
        Wh[(size_t)(n0 + ln) * 512 + k0 + lk] = f2b(Tl[lk][ln]);
    }
    if (blockIdx.x == 0 && blockIdx.y == 0) {
        const void* bsrc = z == 0 ? b0 : (z == 1 ? b1 : (z == 2 ? b2 : b3));
        for (int i = threadIdx.x; i < 512; i += 256)
            bias_f[z * 512 + i] = f32 ? ldin<true>(bsrc, i) : ldin<false>(bsrc, i);
    }
}

// ===========================================================================
// 8-column FFT machinery.
// ===========================================================================
__device__ __forceinline__ int shx(int i, int c) {
    const int x = (i << 2) | c;
    return x ^ (((x >> 6) & 3) << 2);
}

// XCD-paired flat-grid decode.
__device__ __forceinline__ void fft_decode(int flat, int& b, int& dp) {
    const int c8 = flat & 7;
    const int s  = (flat >> 3) & 1;
    const int pp = flat >> 4;            // 0..31
    const int idx = c8 * 32 + pp;        // 0..255
    b  = idx >> 5;
    dp = ((idx & 31) << 1) | s;          // 0..63
}

// Per-stage-PACKED twiddle table: stage m's entries at [2048-2m, 2048-2m+m).
__device__ __forceinline__ void fill_twl(float2* twl, int tid) {
    for (int idx = tid; idx < 2047; idx += 512) {
        const int l2 = 31 - __builtin_clz((unsigned)(2047 - idx));
        const int m = 1 << l2;
        const int k = idx - 2048 + 2 * m;
        float s, c2;
        __sincosf(-3.14159265358979f * (float)k / (float)m, &s, &c2);
        twl[idx] = make_float2(c2, s);
    }
}

// rfft on x: x[b,l,d] -> Xh bf16 PANEL layout:
// panel = plane*512 + b*64 + dp ; addr = (panel*FPAD + f)*8 + (d&7).
__global__ __launch_bounds__(512) void rfft_x(const void* __restrict__ x,
                                              bf16* __restrict__ Xh,
                                              const int* __restrict__ flag)
{
    int b, dp;
    fft_decode(blockIdx.x, b, dp);
    const int d0 = dp * 8;
    __shared__ float2 sh[8192];          // 64 KB
    __shared__ float2 twl[2048];         // 16 KB packed twiddles
    const int tid = threadIdx.x;
    const int c = tid & 3;

    if (*flag) {
        const float* base = (const float*)x + (size_t)b * 2048 * 512 + d0;
        #pragma unroll
        for (int it = 0; it < 8; ++it) {
            const int idx = it * 512 + tid;          // 0..4095
            const int l = idx >> 1, fq = idx & 1;
            const float4 v = *(const float4*)(base + (size_t)l * 512 + fq * 4);
            sh[shx(l, fq * 2)]     = make_float2(v.x, v.y);
            sh[shx(l, fq * 2 + 1)] = make_float2(v.z, v.w);
        }
    } else {
        const bf16* base = (const bf16*)x + (size_t)b * 2048 * 512 + d0;
        #pragma unroll
        for (int it = 0; it < 4; ++it) {
            const int l = it * 512 + tid;
            const short8 v = *(const short8*)(base + (size_t)l * 512);
            #pragma unroll
            for (int q = 0; q < 4; ++q)
                sh[shx(l, q)] = make_float2(s2f(v[2 * q]), s2f(v[2 * q + 1]));
        }
    }
    fill_twl(twl, tid);
    __syncthreads();

    // in-place DIF (natural in, bit-reversed out)
    const int jb = tid >> 2;             // 0..127
    #pragma unroll
    for (int lsm = 10; lsm >= 0; --lsm) {
        const int m = 1 << lsm;
        const int base = 2048 - (m << 1);
        #pragma unroll
        for (int r = 0; r < 8; ++r) {
            const int j  = jb + 128 * r;
            const int k  = j & (m - 1);
            const int i1 = ((j & ~(m - 1)) << 1) | k;
            const int i2 = i1 + m;
            const float2 w = twl[base + k];
            const float cw = w.x, sw = w.y;
            const float2 a  = sh[shx(i1, c)];
            const float2 bb = sh[shx(i2, c)];
            sh[shx(i1, c)] = make_float2(a.x + bb.x, a.y + bb.y);
            const float dx = a.x - bb.x, dy = a.y - bb.y;
            sh[shx(i2, c)] = make_float2(dx * cw - dy * sw, dx * sw + dy * cw);
        }
        __syncthreads();
    }

    // unpack 2-real-signals + bf16 PANEL writes
    const int fb = tid >> 2;
    const size_t pan_re = (size_t)(b * 64 + dp) * FPAD;        // row base (re)
    const size_t pan_im = pan_re + (size_t)512 * FPAD;         // +plane stride
    auto dorow = [&](int f) {
        const int rf = __brev((unsigned)f) >> 21;
        const int rc = __brev((unsigned)((2048 - f) & 2047)) >> 21;
        const float2 Zf = sh[shx(rf, c)];
        const float2 Zc = sh[shx(rc, c)];
        const float x1r = 0.5f * (Zf.x + Zc.x);
        const float x1i = 0.5f * (Zf.y - Zc.y);
        const float x2r = 0.5f * (Zf.y + Zc.y);
        const float x2i = -0.5f * (Zf.x - Zc.x);
        const size_t ro_re = (pan_re + f) * 8 + 2 * c;
        const size_t ro_im = (pan_im + f) * 8 + 2 * c;
        *(unsigned*)&Xh[ro_re] = pk2f(x1r, x2r);
        *(unsigned*)&Xh[ro_im] = pk2f(x1i, x2i);
    };
    #pragma unroll
    for (int it = 0; it < 8; ++it)
        dorow(fb * 8 + it);
    if (tid < 4) dorow(1024);

    // zero pad rows f in [FF, FPAD) for this panel (both planes)
    if (tid < 254) {
        const int f = FF + (tid >> 1);
        const int w = tid & 1;            // 0: re plane, 1: im plane
        const size_t off = (((size_t)(w * 512 + b * 64 + dp)) * FPAD + f) * 8;
        short8 z = {};
        *(short8*)&Xh[off] = z;
    }
}

// ---------------------------------------------------------------------------
// proj_all: ONE dispatch, uniform plain-bf16 GEMM, BK=32 2-PHASE pipeline
// (dbuf 32KB -> ~5 blocks/CU; R14's BK=64/64KB was stuck at 2 blocks/CU with
// Occupancy 17.5% and nothing saturated — occupancy is the lever now).
// gl16 q-swizzle (4-slot, (row&3) XOR), counted vmcnt(4), sibling-XCD
// grouping + T5 setprio (both R14-verified).
// flat grid 1728: per tile-group, sib 0..3 = V, 4..11 = Q/K.
// ---------------------------------------------------------------------------
__global__ __launch_bounds__(256, 4) void proj_all(const bf16* __restrict__ Xh,
                                                   const bf16* __restrict__ WT,
                                                   const float* __restrict__ bias_f,
                                                   bf16* __restrict__ Q,
                                                   bf16* __restrict__ K,
                                                   bf16* __restrict__ Vct)
{
    const int flat = blockIdx.x;          // 0..1727
    const int xcd  = flat & 7;
    const int rest = flat >> 3;           // 0..215
    const int tgrp = rest / 12;           // 0..17
    const int sib  = rest - tgrp * 12;    // 0..11
    const int t    = tgrp * 8 + xcd;      // 0..143
    const bool isV = sib < 4;
    int ny, z;
    if (isV) { ny = sib; z = 2; }
    else { const int s = sib - 4; z = s >> 2; ny = s & 3; }

    const int pb = t / 9;                // 0..15
    const int f0 = (t - pb * 9) * 128;
    const int plane = pb >> 3, b = pb & 7;
    const int n0 = ny * 128;
    const int tid = threadIdx.x, wv = tid >> 6, lane = tid & 63;
    const int wm = (wv >> 1) * 64, wn = (wv & 1) * 64;
    const size_t pbase = (size_t)pb * PSTRIDE;

    const bf16* Bh = WT + (size_t)z * 524288;
    const float* bias = bias_f + z * 512;

    __shared__ __align__(1024) bf16 SH[16384];   // 32 KB: 2 x (A 8KB | B 8KB)

    const int r4 = lane >> 2;         // row within 16-row chunk
    const int sl = lane & 3;          // dest slot (of 4 qwords/row)
    const int q  = sl ^ (r4 & 3);     // logical qword fetched (swizzled source)
    const int r16 = lane & 15, cc = lane >> 4;
    const int rs4 = r16 & 3;
    const int nn2 = lane & 15, rq = (lane >> 4) * 4;

    auto STAGE = [&](int buf, int kt) {
        char* base = (char*)SH + buf * 16384;
        #pragma unroll
        for (int c2 = 0; c2 < 2; ++c2) {
            const int chunk = wv * 2 + c2;            // 0..7
            const int row = chunk * 16 + r4;
            gl16(&Xh[pbase + ((size_t)((kt >> 3) + q) * FPAD + f0 + row) * 8],
                 base + chunk * 1024);
            gl16(&Bh[(size_t)(n0 + row) * 512 + kt + q * 8],
                 base + 8192 + chunk * 1024);
        }
    };

    f32x4 acc[4][4] = {};
    STAGE(0, 0);
    for (int it = 0; it < 16; ++it) {
        if (it < 15) {
            STAGE((it + 1) & 1, (it + 1) * 32);
            asm volatile("s_waitcnt vmcnt(4)" ::: "memory");   // current 4 landed
        } else {
            asm volatile("s_waitcnt vmcnt(0)" ::: "memory");
        }
        __builtin_amdgcn_s_barrier();
        __builtin_amdgcn_sched_barrier(0);

        const bf16* Ab = SH + (it & 1) * 8192;
        const bf16* Bb = Ab + 4096;
        __builtin_amdgcn_s_setprio(1);
        {
            short8 af[4], bfr[4];
            const int sa = (cc ^ rs4) * 8;
            #pragma unroll
            for (int i = 0; i < 4; ++i) {
                af[i]  = *(const short8*)&Ab[(wm + i * 16 + r16) * 32 + sa];
                bfr[i] = *(const short8*)&Bb[(wn + i * 16 + r16) * 32 + sa];
            }
            #pragma unroll
            for (int i = 0; i < 4; ++i)
                #pragma unroll
                for (int j = 0; j < 4; ++j)
                    acc[i][j] = MFMA16(af[i], bfr[j], acc[i][j]);
        }
        __builtin_amdgcn_s_setprio(0);
        asm volatile("s_waitcnt lgkmcnt(0)" ::: "memory");
        __builtin_amdgcn_s_barrier();      // reads done before buffer overwrite
    }

    if (!isV) {
        // ----- Q/K epilogue: pre-swizzled bf16 planes for att's gl16 -----
        bf16* dst = z == 0 ? Q : K;
        const size_t SPQ = (size_t)BB * FF * DD;
        #pragma unroll
        for (int i = 0; i < 4; ++i)
            #pragma unroll
            for (int j = 0; j < 4; ++j) {
                const int col = n0 + wn + j * 16 + nn2;
                #pragma unroll
                for (int r = 0; r < 4; ++r) {
                    const int f = f0 + wm + i * 16 + rq + r;
                    if (f < FF) {
                        float v = acc[i][j][r];
                        if (plane == 0 && f == 0) v += 2048.0f * bias[col];
                        const int swz = ((f >> 1) & 3) << 3;
                        dst[(size_t)plane * SPQ + ((size_t)(b * FF + f)) * 512 + (col ^ swz)] = f2b(v);
                    }
                }
            }
    } else {
        // ----- V epilogue: transpose via LDS (full 32KB), write Vct[b,n,g] -----
        bf16* T = SH;
        __syncthreads();
        #pragma unroll
        for (int i = 0; i < 4; ++i)
            #pragma unroll
            for (int j = 0; j < 4; ++j) {
                const int col_l = wn + j * 16 + nn2;
                #pragma unroll
                for (int r = 0; r < 4; ++r) {
                    const int row_l = wm + i * 16 + rq + r;
                    const int f = f0 + row_l;
                    float v = (f < FF) ? acc[i][j][r] : 0.f;
                    if (plane == 0 && f == 0) v += 2048.0f * bias[n0 + col_l];
                    T[col_l * 128 + (row_l ^ ((col_l & 15) << 3))] = f2b(v);
                }
            }
        __syncthreads();

        const int nl = tid >> 1, half = tid & 1;
        const size_t gbase = ((size_t)(b * 1024 + plane * 512 + n0 + nl)) * GP + f0;
        #pragma unroll
        for (int a = 0; a < 8; ++a) {
            const int fl = half * 64 + a * 8;
            if (f0 + fl < GP) {
                const short8 v8 = *(const short8*)&T[nl * 128 + (fl ^ ((nl & 15) << 3))];
                *(short8*)&Vct[gbase + fl] = v8;
            }
        }
    }
}

// ---------------------------------------------------------------------------
// att_mfma: plain bf16, 2 planes. 128f x 64g block, 4 waves, BK=64
// (2 half-tiles of 32k each; 16 barriers). 48KB LDS, 2 blocks/CU.
// R12/R14-measured-best form.
// ---------------------------------------------------------------------------
__global__ __launch_bounds__(256, 2) void att_mfma(const bf16* __restrict__ Asp,
                                                   const bf16* __restrict__ Bsp,
                                                   float* __restrict__ att)
{
    const size_t SP = (size_t)BB * FF * DD;
    const int flat = blockIdx.x;
    const int b    = flat & 7;
    const int slot = flat >> 3;          // 0..152
    const int grp  = slot / 51;          // 0..2
    const int rem  = slot % 51;
    const int g    = rem / 3;            // 0..16
    const int r3   = rem % 3;
    const int ft   = grp * 3 + r3;       // 0..8
    const int f0 = ft * 128, g0 = g * 64;

    const int tid = threadIdx.x;
    const int wv = tid >> 6, lane = tid & 63;
    const int wvf = wv >> 1, wvg = wv & 1;

    // A: 2 halves x 16KB | B: 2 halves x 8KB  = 48 KB
    __shared__ __align__(1024) char LB[49152];

    f32x4 accr[4][2] = {}; f32x4 acci[4][2] = {};

    const int r16 = lane & 15, cc = lane >> 4;
    const int rpos = (cc ^ ((r16 >> 1) & 3)) * 8;
    const size_t abase = (size_t)(b * FF + f0) * 512;
    const size_t bbase = (size_t)(b * FF + g0) * 512;
    const int lrow = lane >> 2;          // 0..15 within a 16-row chunk
    const int lcol = (lane & 3) * 8;     // element offset of this lane's 16B

    for (int kt = 0; kt < 512; kt += 64) {
        // A: 32 chunks (2 halves x 2 planes x 8 row-groups); 8 per wave
        #pragma unroll
        for (int c2 = 0; c2 < 8; ++c2) {
            const int chunk = wv * 8 + c2;            // 0..31
            const int half = chunk >> 4;
            const int pl = (chunk >> 3) & 1, rg = chunk & 7;
            const int row = rg * 16 + lrow;
            gl16(&Asp[(size_t)pl * SP + abase + (size_t)row * 512 + kt + half * 32 + lcol],
                 LB + half * 16384 + ((pl << 3) | rg) * 1024);
        }
        // B: 16 chunks (2 halves x 2 planes x 4 row-groups); 4 per wave
        #pragma unroll
        for (int c2 = 0; c2 < 4; ++c2) {
            const int chunk = wv * 4 + c2;            // 0..15
            const int half = chunk >> 3;
            const int pl = (chunk >> 2) & 1, rg = chunk & 3;
            const int row = rg * 16 + lrow;
            gl16(&Bsp[(size_t)pl * SP + bbase + (size_t)row * 512 + kt + half * 32 + lcol],
                 LB + 32768 + half * 8192 + ((pl << 2) | rg) * 1024);
        }
        __syncthreads();

        #pragma unroll
        for (int kk = 0; kk < 2; ++kk) {
            bf16 (*Al)[128][32] = (bf16(*)[128][32])(LB + kk * 16384);
            bf16 (*Bl)[64][32]  = (bf16(*)[64][32])(LB + 32768 + kk * 8192);
            short8 aA[4][2], bB[2][2], nb[2];
            #pragma unroll
            for (int i = 0; i < 4; ++i) {
                const int row = wvf * 64 + i * 16 + r16;
                #pragma unroll
                for (int pl = 0; pl < 2; ++pl)
                    aA[i][pl] = *(const short8*)&Al[pl][row][rpos];
            }
            #pragma unroll
            for (int j = 0; j < 2; ++j) {
                const int row = wvg * 32 + j * 16 + r16;
                #pragma unroll
                for (int pl = 0; pl < 2; ++pl)
                    bB[j][pl] = *(const short8*)&Bl[pl][row][rpos];
                nb[j] = neg8(bB[j][1]);
            }
            #pragma unroll
            for (int i = 0; i < 4; ++i)
                #pragma unroll
                for (int j = 0; j < 2; ++j) {
                    accr[i][j] = MFMA16(aA[i][0], bB[j][0], accr[i][j]);
                    accr[i][j] = MFMA16(aA[i][1], nb[j],    accr[i][j]);
                    acci[i][j] = MFMA16(aA[i][0], bB[j][1], acci[i][j]);
                    acci[i][j] = MFMA16(aA[i][1], bB[j][0], acci[i][j]);
                }
        }
        __syncthreads();
    }

    const int rq = (lane >> 4) * 4;
    #pragma unroll
    for (int i = 0; i < 4; ++i)
        #pragma unroll
        for (int j = 0; j < 2; ++j)
            #pragma unroll
            for (int r = 0; r < 4; ++r) {
                const int f = f0 + wvf * 64 + i * 16 + rq + r;
                const int gg = g0 + wvg * 32 + j * 16 + r16;
                if (f < FF && gg < FF) {
                    const float ar = accr[i][j][r];
                    const float ai = acci[i][j][r];
                    att[((size_t)(b * FF + f)) * FF + gg] = ATT_SCALE * sqrtf(ar * ar + ai * ai);
                }
            }
}

// ---------------------------------------------------------------------------
// softmax over g per (b,f) row; LDS-staged; exp stored back (single expf pass).
// ---------------------------------------------------------------------------
__global__ __launch_bounds__(256) void softmax_rows(const float* __restrict__ att,
                                                    bf16* __restrict__ att16)
{
    const int row = blockIdx.x;
    const float* p = att + (size_t)row * FF;
    bf16* q = att16 + (size_t)row * GP;
    const int tid = threadIdx.x;
    const int lane = tid & 63, wid = tid >> 6;
    __shared__ float srow[1028];
    __shared__ float red[4];

    float m = -1e30f;
    for (int i = tid; i < FF; i += 256) {
        const float v = p[i];
        srow[i] = v;
        m = fmaxf(m, v);
    }
    #pragma unroll
    for (int o = 32; o; o >>= 1) m = fmaxf(m, __shfl_down(m, o));
    if (lane == 0) red[wid] = m;
    __syncthreads();
    m = fmaxf(fmaxf(red[0], red[1]), fmaxf(red[2], red[3]));
    __syncthreads();

    float s = 0.f;
    for (int i = tid; i < FF; i += 256) {
        const float e = expf(srow[i] - m);
        srow[i] = e;                      // own indices only — no race
        s += e;
    }
    #pragma unroll
    for (int o = 32; o; o >>= 1) s += __shfl_down(s, o);
    if (lane == 0) red[wid] = s;
    __syncthreads();
    s = red[0] + red[1] + red[2] + red[3];
    const float inv = 1.f / s;
    for (int i = tid; i < GP; i += 256)
        q[i] = f2b(i < FF ? srow[i] * inv : 0.f);
}

// ---------------------------------------------------------------------------
// ctx_mfma: 128f x 64n block, 4 waves, BK=64, gl16 staging, 2-PHASE pipeline
// (dbuf 48KB, counted vmcnt(6)) + T5 setprio. OOB f-rows -> discarded rows.
// Writes out-GEMM-ready bf16 Csp, row = (plane*8+b)*FPAD + f.
// ---------------------------------------------------------------------------
__global__ __launch_bounds__(256, 2) void ctx_mfma(const bf16* __restrict__ att16,
                                                   const bf16* __restrict__ Vct,
                                                   bf16* __restrict__ Csp)
{
    const int flat = blockIdx.x;          // 1152 blocks
    const int b    = flat & 7;
    const int slot = flat >> 3;           // 0..143
    const int ft   = slot >> 4;           // 0..8
    const int nt   = slot & 15;           // 0..15
    const int f0 = ft * 128, n0 = nt * 64;

    const int tid = threadIdx.x;
    const int wv = tid >> 6, lane = tid & 63;
    const int wvf = wv >> 1, wvg = wv & 1;

    __shared__ __align__(1024) bf16 SH[24576];   // 48 KB: 2 x (A 16KB | B 8KB)

    f32x4 acc[4][2] = {};
    const int r8 = lane >> 3, sl = lane & 7, q = sl ^ r8;
    const int r16 = lane & 15, cc = lane >> 4;
    const int rs8 = r16 & 7;

    auto STAGE = [&](int buf, int kt) {
        char* base = (char*)SH + buf * 24576;
        #pragma unroll
        for (int c2 = 0; c2 < 4; ++c2) {
            const int chunk = wv * 4 + c2;        // 0..15
            const int row = chunk * 8 + r8;
            gl16(&att16[((size_t)(b * FF + f0 + row)) * GP + kt + q * 8],
                 base + chunk * 1024);
        }
        #pragma unroll
        for (int c2 = 0; c2 < 2; ++c2) {
            const int chunk = wv * 2 + c2;        // 0..7
            const int row = chunk * 8 + r8;
            gl16(&Vct[((size_t)(b * 1024 + n0 + row)) * GP + kt + q * 8],
                 base + 16384 + chunk * 1024);
        }
    };

    STAGE(0, 0);
    for (int it = 0; it < 17; ++it) {        // GP/64 = 17
        if (it < 16) {
            STAGE((it + 1) & 1, (it + 1) * 64);
            asm volatile("s_waitcnt vmcnt(6)" ::: "memory");
        } else {
            asm volatile("s_waitcnt vmcnt(0)" ::: "memory");
        }
        __builtin_amdgcn_s_barrier();
        __builtin_amdgcn_sched_barrier(0);

        const bf16* Ab = SH + (it & 1) * 12288;
        const bf16* Bb = Ab + 8192;
        __builtin_amdgcn_s_setprio(1);
        #pragma unroll
        for (int kk = 0; kk < 2; ++kk) {
            short8 aA[4], bB[2];
            const int sa = ((kk * 4 + cc) ^ rs8) * 8;
            #pragma unroll
            for (int i = 0; i < 4; ++i)
                aA[i] = *(const short8*)&Ab[(wvf * 64 + i * 16 + r16) * 64 + sa];
            #pragma unroll
            for (int j = 0; j < 2; ++j)
                bB[j] = *(const short8*)&Bb[(wvg * 32 + j * 16 + r16) * 64 + sa];
            #pragma unroll
            for (int i = 0; i < 4; ++i)
                #pragma unroll
                for (int j = 0; j < 2; ++j)
                    acc[i][j] = MFMA16(aA[i], bB[j], acc[i][j]);
        }
        __builtin_amdgcn_s_setprio(0);
        asm volatile("s_waitcnt lgkmcnt(0)" ::: "memory");
        __builtin_amdgcn_s_barrier();
    }

    const int rq = (lane >> 4) * 4;
    #pragma unroll
    for (int i = 0; i < 4; ++i)
        #pragma unroll
        for (int j = 0; j < 2; ++j)
            #pragma unroll
            for (int r = 0; r < 4; ++r) {
                const int f = f0 + wvf * 64 + i * 16 + rq + r;
                const int n = n0 + wvg * 32 + j * 16 + r16;
                if (f < FF) {
                    const int d = n & 511, pl = n >> 9;
                    Csp[((size_t)(pl * 8 + b) * FPAD + f) * 512 + d] = f2b(acc[i][j][r]);
                }
            }
}

// ---------------------------------------------------------------------------
// out_mfma_freq: Cw = Csp(bf16) @ WoT. 128x64 tiles (144x8 grid), BK=64,
// gl16 staging, 2-PHASE pipeline (dbuf 48KB, counted vmcnt(6)) + T5 setprio.
// ---------------------------------------------------------------------------
__global__ __launch_bounds__(256, 2) void out_mfma_freq(const bf16* __restrict__ A,
                                                        const bf16* __restrict__ BhT,
                                                        float* __restrict__ CwR,
                                                        float* __restrict__ CwI)
{
    const int t = blockIdx.x;            // 0..143
    const int pb = t / 9;
    const int f0 = (t - pb * 9) * 128;
    const int plane = pb >> 3, b = pb & 7;
    const int m0 = t * 128, n0 = blockIdx.y * 64;
    const int tid = threadIdx.x, wv = tid >> 6, lane = tid & 63;
    const int wvf = wv >> 1, wvg = wv & 1;

    __shared__ __align__(1024) bf16 SH[24576];   // 48 KB: 2 x (A 16KB | B 8KB)

    f32x4 acc[4][2] = {};
    const int r8 = lane >> 3, sl = lane & 7, q = sl ^ r8;
    const int r16 = lane & 15, cc = lane >> 4;
    const int rs8 = r16 & 7;

    auto STAGE = [&](int buf, int kt) {
        char* base = (char*)SH + buf * 24576;
        #pragma unroll
        for (int c2 = 0; c2 < 4; ++c2) {
            const int chunk = wv * 4 + c2;        // 0..15
            const int row = chunk * 8 + r8;
            gl16(&A[(size_t)(m0 + row) * 512 + kt + q * 8],
                 base + chunk * 1024);
        }
        #pragma unroll
        for (int c2 = 0; c2 < 2; ++c2) {
            const int chunk = wv * 2 + c2;        // 0..7
            const int row = chunk * 8 + r8;
            gl16(&BhT[(size_t)(n0 + row) * 512 + kt + q * 8],
                 base + 16384 + chunk * 1024);
        }
    };

    STAGE(0, 0);
    for (int it = 0; it < 8; ++it) {
        if (it < 7) {
            STAGE((it + 1) & 1, (it + 1) * 64);
            asm volatile("s_waitcnt vmcnt(6)" ::: "memory");
        } else {
            asm volatile("s_waitcnt vmcnt(0)" ::: "memory");
        }
        __builtin_amdgcn_s_barrier();
        __builtin_amdgcn_sched_barrier(0);

        const bf16* Ab = SH + (it & 1) * 12288;
        const bf16* Bb = Ab + 8192;
        __builtin_amdgcn_s_setprio(1);
        #pragma unroll
        for (int kk = 0; kk < 2; ++kk) {
            short8 af[4], bfr[2];
            const int sa = ((kk * 4 + cc) ^ rs8) * 8;
            #pragma unroll
            for (int i = 0; i < 4; ++i)
                af[i] = *(const short8*)&Ab[(wvf * 64 + i * 16 + r16) * 64 + sa];
            #pragma unroll
            for (int j = 0; j < 2; ++j)
                bfr[j] = *(const short8*)&Bb[(wvg * 32 + j * 16 + r16) * 64 + sa];
            #pragma unroll
            for (int i = 0; i < 4; ++i)
                #pragma unroll
                for (int j = 0; j < 2; ++j)
                    acc[i][j] = MFMA16(af[i], bfr[j], acc[i][j]);
        }
        __builtin_amdgcn_s_setprio(0);
        asm volatile("s_waitcnt lgkmcnt(0)" ::: "memory");
        __builtin_amdgcn_s_barrier();
    }

    float* dst = plane ? CwI : CwR;
    const int nn2 = lane & 15, rq = (lane >> 4) * 4;
    #pragma unroll
    for (int i = 0; i < 4; ++i)
        #pragma unroll
        for (int j = 0; j < 2; ++j) {
            const int col = n0 + wvg * 32 + j * 16 + nn2;
            #pragma unroll
            for (int r = 0; r < 4; ++r) {
                const int f = f0 + wvf * 64 + i * 16 + rq + r;
                if (f < FF)
                    dst[((size_t)(b * FF + f)) * 512 + col] = acc[i][j][r];
            }
        }
}

// ---------------------------------------------------------------------------
// irfft8: Cw planes -> time domain, + bo, writes d_out (flag dtype).
// ---------------------------------------------------------------------------
__global__ __launch_bounds__(512) void irfft8(const float* __restrict__ CwR,
                                              const float* __restrict__ CwI,
                                              void* __restrict__ out,
                                              const float* __restrict__ bias_f,
                                              const int* __restrict__ flag)
{
    int b, dp;
    fft_decode(blockIdx.x, b, dp);
    const int d0 = dp * 8;
    __shared__ float2 sh[8192];
    __shared__ float2 twl[2048];
    const int tid = threadIdx.x;
    const int c = tid & 3, fb = tid >> 2;

    // hermitian construct
    for (int it = 0; it < 9; ++it) {
        const int f = fb + 128 * it;
        if (f < FF) {
            const size_t off = ((size_t)(b * FF + f)) * 512 + d0 + 2 * c;
            const float2 vr = *(const float2*)(CwR + off);
            const float2 vi = *(const float2*)(CwI + off);
            float c1x = vr.x, c1y = vi.x, c2x = vr.y, c2y = vi.y;
            if (f == 0 || f == 1024) { c1y = 0.f; c2y = 0.f; }
            sh[shx(f, c)] = make_float2(c1x - c2y, c1y + c2x);
            if (f >= 1 && f <= 1023)
                sh[shx(2048 - f, c)] = make_float2(c1x + c2y, c2x - c1y);
        }
    }
    fill_twl(twl, tid);
    __syncthreads();

    // inverse DIF (conjugated twiddles: sw = -w.y)
    const int jb = fb;
    #pragma unroll
    for (int lsm = 10; lsm >= 0; --lsm) {
        const int m = 1 << lsm;
        const int base = 2048 - (m << 1);
        #pragma unroll
        for (int r = 0; r < 8; ++r) {
            const int j  = jb + 128 * r;
            const int k  = j & (m - 1);
            const int i1 = ((j & ~(m - 1)) << 1) | k;
            const int i2 = i1 + m;
            const float2 w = twl[base + k];
            const float cw = w.x, sw = -w.y;
            const float2 a  = sh[shx(i1, c)];
            const float2 bb = sh[shx(i2, c)];
            sh[shx(i1, c)] = make_float2(a.x + bb.x, a.y + bb.y);
            const float dx = a.x - bb.x, dy = a.y - bb.y;
            sh[shx(i2, c)] = make_float2(dx * cw - dy * sw, dx * sw + dy * cw);
        }
        __syncthreads();
    }

    // write + bo
    const float sc = 1.0f / 2048.0f;
    const float bo0 = bias_f[1536 + d0 + 2 * c];
    const float bo1 = bias_f[1536 + d0 + 2 * c + 1];
    const bool f32o = (*flag) != 0;
    const int lb = tid >> 2;
    #pragma unroll
    for (int it = 0; it < 16; ++it) {
        const int l  = lb * 16 + it;
        const int rl = __brev((unsigned)l) >> 21;
        const float2 z = sh[shx(rl, c)];
        const float o0 = z.x * sc + bo0;
        const float o1 = z.y * sc + bo1;
        const size_t off = ((size_t)(b * 2048 + l)) * 512 + d0 + 2 * c;
        if (f32o) {
            *(float2*)((float*)out + off) = make_float2(o0, o1);
        } else {
            __hip_bfloat162 h;
            h.x = f2b(o0); h.y = f2b(o1);
            *(__hip_bfloat162*)((bf16*)out + off) = h;
        }
    }
}

// ---------------------------------------------------------------------------
// launch — freq-domain pipeline, 9 dispatches (prep_bias folded into split_w).
// Regions:
//   A [0, 33.65MB):   attn (att out)
//   B [+37.75MB):     Xh (rfft_x out, panel layout) -> att16 | Csp
//   C [+17.04MB):     Asp -> CwR
//   D [+17.04MB):     Bsp -> CwI
//   E [+17.83MB):     Vct (8192 rows x GP=1088 x 2B = 17,825,792 exactly)
//   W [+4.2MB]:       WT, bias_f, flag
// ---------------------------------------------------------------------------
extern "C" void kernel_launch(void* const* d_in, const int* in_sizes, int n_in,
                              void* d_out, int out_size, void* d_ws, size_t ws_size,
                              hipStream_t stream)
{
    const void* x  = d_in[0];
    const void* Wq = d_in[1]; const void* bq = d_in[2];
    const void* Wk = d_in[3]; const void* bk = d_in[4];
    const void* Wv = d_in[5]; const void* bv = d_in[6];
    const void* Wo = d_in[7]; const void* bo = d_in[8];

    char* ws = (char*)d_ws;
    char* pA = ws;                          // 33,652,736
    char* pB = pA + 33652736;               // 37,748,736
    char* pC = pB + 37748736;               // 17,039,360
    char* pD = pC + 17039360;               // 17,039,360
    char* pE = pD + 17039360;               // 17,825,792
    char* pW = pE + 17825792;

    float*  attn = (float*)pA;
    bf16*   Xh   = (bf16*)pB;
    bf16*   att16= (bf16*)pB;                       // 8200*1088*2 = 17,843,200 B
    bf16*   Csp  = (bf16*)(pB + 17843200);          // + 18,874,368 <= region end
    bf16*   Asp  = (bf16*)pC;
    bf16*   Bsp  = (bf16*)pD;
    float*  CwR  = (float*)pC;
    float*  CwI  = (float*)pD;
    bf16*   Vct  = (bf16*)pE;
    bf16*   WT   = (bf16*)pW;
    float*  bias_f = (float*)(pW + 4194304);
    int*    flag = (int*)(pW + 4194304 + 8192);

    detect_dtype<<<1, 256, 0, stream>>>((const unsigned short*)x, flag);
    split_w_t<<<dim3(16, 16, 4), 256, 0, stream>>>(Wq, Wk, Wv, Wo, bq, bk, bv, bo,
                                                   WT, bias_f, flag);
    rfft_x<<<dim3(512), 512, 0, stream>>>(x, Xh, flag);
    proj_all<<<dim3(1728), 256, 0, stream>>>(Xh, WT, bias_f, Asp, Bsp, Vct);
    att_mfma<<<dim3(1224), 256, 0, stream>>>(Asp, Bsp, attn);
    softmax_rows<<<dim3(BB * FF), 256, 0, stream>>>(attn, att16);
    ctx_mfma<<<dim3(1152), 256, 0, stream>>>(att16, Vct, Csp);
    out_mfma_freq<<<dim3(144, 8), 256, 0, stream>>>(Csp, WT + 3 * 524288, CwR, CwI);
    irfft8<<<dim3(512), 512, 0, stream>>>(CwR, CwI, d_out, bias_f, flag);
}

// Round 16
// 311.966 us; speedup vs baseline: 1.0690x; 1.0690x over previous
//
#include <hip/hip_runtime.h>
#include <hip/hip_bf16.h>
#include <math.h>

typedef __hip_bfloat16 bf16;
typedef __attribute__((ext_vector_type(8))) short short8;
typedef __attribute__((ext_vector_type(4))) float f32x4;

#define BB 8
#define LL 2048
#define DD 512
#define FF 1025   // LL/2+1
#define GP 1088   // g padded to 17*64 for ctx BK=64 K-chunks
#define FPAD 1152 // freq rows padded per (plane,b): 9 tiles of 128
#define PSTRIDE 589824   // pb panel-block stride = 64*FPAD*8 elements
#define ATT_SCALE 0.04419417382415922f   // 512^-0.5

__device__ __forceinline__ float b2f(bf16 v) { return __bfloat162float(v); }
__device__ __forceinline__ bf16  f2b(float v) { return __float2bfloat16(v); }
__device__ __forceinline__ float s2f(short s) { bf16 t; *reinterpret_cast<short*>(&t) = s; return b2f(t); }
__device__ __forceinline__ unsigned pk2f(float a, float b) {
    bf16 ha = f2b(a), hb = f2b(b);
    return (unsigned)*(unsigned short*)&ha | ((unsigned)*(unsigned short*)&hb << 16);
}

#define MFMA16(a, b, c) __builtin_amdgcn_mfma_f32_16x16x32_bf16((a), (b), (c), 0, 0, 0)

// exact bf16 negation of an 8-element fragment (sign-bit flip)
__device__ __forceinline__ short8 neg8(short8 v) {
    short8 r;
    #pragma unroll
    for (int t = 0; t < 8; ++t) r[t] = (short)(v[t] ^ (short)0x8000);
    return r;
}

// async global->LDS: 16B per lane, dest = wave-uniform base + lane*16 (linear)
typedef __attribute__((address_space(1))) const unsigned int gu32;
typedef __attribute__((address_space(3))) unsigned int lu32;
__device__ __forceinline__ void gl16(const void* g, void* l) {
    __builtin_amdgcn_global_load_lds((gu32*)g, (lu32*)l, 16, 0, 0);
}

template<bool F32>
__device__ __forceinline__ float ldin(const void* p, size_t i) {
    if (F32) return ((const float*)p)[i];
    else     return b2f(((const bf16*)p)[i]);
}

// ---------------------------------------------------------------------------
// dtype detector (flag: 1 = fp32 inputs, 0 = bf16).
// ---------------------------------------------------------------------------
__global__ __launch_bounds__(256) void detect_dtype(const unsigned short* __restrict__ x,
                                                    int* __restrict__ flag)
{
    __shared__ int cnt[256];
    int c = 0;
    for (int i = threadIdx.x; i < 4096; i += 256) {
        const int e = (x[i] >> 7) & 0xFF;
        c += (e >= 100 && e <= 150) ? 1 : 0;
    }
    cnt[threadIdx.x] = c;
    __syncthreads();
    for (int s = 128; s; s >>= 1) {
        if (threadIdx.x < s) cnt[threadIdx.x] += cnt[threadIdx.x + s];
        __syncthreads();
    }
    if (threadIdx.x == 0) *flag = (cnt[0] < 3400) ? 1 : 0;
}

// ---------------------------------------------------------------------------
// split_w_t (+ fused bias prep): W[512,512] -> transposed bf16 plane WT[n][k];
// block (0,0,z) also writes bias_f[z*512..].
// ---------------------------------------------------------------------------
__global__ __launch_bounds__(256) void split_w_t(const void* __restrict__ W0,
                                                 const void* __restrict__ W1,
                                                 const void* __restrict__ W2,
                                                 const void* __restrict__ W3,
                                                 const void* __restrict__ b0,
                                                 const void* __restrict__ b1,
                                                 const void* __restrict__ b2,
                                                 const void* __restrict__ b3,
                                                 bf16* __restrict__ WT,
                                                 float* __restrict__ bias_f,
                                                 const int* __restrict__ flag)
{
    const int z = blockIdx.z;
    const void* W = z == 0 ? W0 : (z == 1 ? W1 : (z == 2 ? W2 : W3));
    bf16* Wh = WT + (size_t)z * 524288;
    const int k0 = blockIdx.x * 32, n0 = blockIdx.y * 32;
    const bool f32 = (*flag) != 0;
    __shared__ float Tl[32][33];
    for (int it = 0; it < 4; ++it) {
        const int idx = it * 256 + threadIdx.x;
        const int lk = idx >> 5, ln = idx & 31;
        Tl[lk][ln] = f32 ? ldin<true>(W, (size_t)(k0 + lk) * 512 + n0 + ln)
                         : ldin<false>(W, (size_t)(k0 + lk) * 512 + n0 + ln);
    }
    __syncthreads();
    for (int it = 0; it < 4; ++it) {
        const int idx = it * 256 + threadIdx.x;
        const int ln = idx >> 5, lk = idx & 31;
        Wh[(size_t)(n0 + ln) * 512 + k0 + lk] = f2b(Tl[lk][ln]);
    }
    if (blockIdx.x == 0 && blockIdx.y == 0) {
        const void* bsrc = z == 0 ? b0 : (z == 1 ? b1 : (z == 2 ? b2 : b3));
        for (int i = threadIdx.x; i < 512; i += 256)
            bias_f[z * 512 + i] = f32 ? ldin<true>(bsrc, i) : ldin<false>(bsrc, i);
    }
}

// ===========================================================================
// 8-column FFT machinery.
// ===========================================================================
__device__ __forceinline__ int shx(int i, int c) {
    const int x = (i << 2) | c;
    return x ^ (((x >> 6) & 3) << 2);
}

// XCD-paired flat-grid decode.
__device__ __forceinline__ void fft_decode(int flat, int& b, int& dp) {
    const int c8 = flat & 7;
    const int s  = (flat >> 3) & 1;
    const int pp = flat >> 4;            // 0..31
    const int idx = c8 * 32 + pp;        // 0..255
    b  = idx >> 5;
    dp = ((idx & 31) << 1) | s;          // 0..63
}

// Per-stage-PACKED twiddle table: stage m's entries at [2048-2m, 2048-2m+m).
__device__ __forceinline__ void fill_twl(float2* twl, int tid) {
    for (int idx = tid; idx < 2047; idx += 512) {
        const int l2 = 31 - __builtin_clz((unsigned)(2047 - idx));
        const int m = 1 << l2;
        const int k = idx - 2048 + 2 * m;
        float s, c2;
        __sincosf(-3.14159265358979f * (float)k / (float)m, &s, &c2);
        twl[idx] = make_float2(c2, s);
    }
}

// rfft on x: x[b,l,d] -> Xh bf16 PANEL layout:
// panel = plane*512 + b*64 + dp ; addr = (panel*FPAD + f)*8 + (d&7).
__global__ __launch_bounds__(512) void rfft_x(const void* __restrict__ x,
                                              bf16* __restrict__ Xh,
                                              const int* __restrict__ flag)
{
    int b, dp;
    fft_decode(blockIdx.x, b, dp);
    const int d0 = dp * 8;
    __shared__ float2 sh[8192];          // 64 KB
    __shared__ float2 twl[2048];         // 16 KB packed twiddles
    const int tid = threadIdx.x;
    const int c = tid & 3;

    if (*flag) {
        const float* base = (const float*)x + (size_t)b * 2048 * 512 + d0;
        #pragma unroll
        for (int it = 0; it < 8; ++it) {
            const int idx = it * 512 + tid;          // 0..4095
            const int l = idx >> 1, fq = idx & 1;
            const float4 v = *(const float4*)(base + (size_t)l * 512 + fq * 4);
            sh[shx(l, fq * 2)]     = make_float2(v.x, v.y);
            sh[shx(l, fq * 2 + 1)] = make_float2(v.z, v.w);
        }
    } else {
        const bf16* base = (const bf16*)x + (size_t)b * 2048 * 512 + d0;
        #pragma unroll
        for (int it = 0; it < 4; ++it) {
            const int l = it * 512 + tid;
            const short8 v = *(const short8*)(base + (size_t)l * 512);
            #pragma unroll
            for (int q = 0; q < 4; ++q)
                sh[shx(l, q)] = make_float2(s2f(v[2 * q]), s2f(v[2 * q + 1]));
        }
    }
    fill_twl(twl, tid);
    __syncthreads();

    // in-place DIF (natural in, bit-reversed out)
    const int jb = tid >> 2;             // 0..127
    #pragma unroll
    for (int lsm = 10; lsm >= 0; --lsm) {
        const int m = 1 << lsm;
        const int base = 2048 - (m << 1);
        #pragma unroll
        for (int r = 0; r < 8; ++r) {
            const int j  = jb + 128 * r;
            const int k  = j & (m - 1);
            const int i1 = ((j & ~(m - 1)) << 1) | k;
            const int i2 = i1 + m;
            const float2 w = twl[base + k];
            const float cw = w.x, sw = w.y;
            const float2 a  = sh[shx(i1, c)];
            const float2 bb = sh[shx(i2, c)];
            sh[shx(i1, c)] = make_float2(a.x + bb.x, a.y + bb.y);
            const float dx = a.x - bb.x, dy = a.y - bb.y;
            sh[shx(i2, c)] = make_float2(dx * cw - dy * sw, dx * sw + dy * cw);
        }
        __syncthreads();
    }

    // unpack 2-real-signals + bf16 PANEL writes
    const int fb = tid >> 2;
    const size_t pan_re = (size_t)(b * 64 + dp) * FPAD;        // row base (re)
    const size_t pan_im = pan_re + (size_t)512 * FPAD;         // +plane stride
    auto dorow = [&](int f) {
        const int rf = __brev((unsigned)f) >> 21;
        const int rc = __brev((unsigned)((2048 - f) & 2047)) >> 21;
        const float2 Zf = sh[shx(rf, c)];
        const float2 Zc = sh[shx(rc, c)];
        const float x1r = 0.5f * (Zf.x + Zc.x);
        const float x1i = 0.5f * (Zf.y - Zc.y);
        const float x2r = 0.5f * (Zf.y + Zc.y);
        const float x2i = -0.5f * (Zf.x - Zc.x);
        const size_t ro_re = (pan_re + f) * 8 + 2 * c;
        const size_t ro_im = (pan_im + f) * 8 + 2 * c;
        *(unsigned*)&Xh[ro_re] = pk2f(x1r, x2r);
        *(unsigned*)&Xh[ro_im] = pk2f(x1i, x2i);
    };
    #pragma unroll
    for (int it = 0; it < 8; ++it)
        dorow(fb * 8 + it);
    if (tid < 4) dorow(1024);

    // zero pad rows f in [FF, FPAD) for this panel (both planes)
    if (tid < 254) {
        const int f = FF + (tid >> 1);
        const int w = tid & 1;            // 0: re plane, 1: im plane
        const size_t off = (((size_t)(w * 512 + b * 64 + dp)) * FPAD + f) * 8;
        short8 z = {};
        *(short8*)&Xh[off] = z;
    }
}

// ---------------------------------------------------------------------------
// proj_all: ONE dispatch, uniform plain-bf16 GEMM, BK=32 2-PHASE pipeline
// (dbuf 32KB -> ~4-5 blocks/CU). SWIZZLE FIX vs R15: slot XOR uses
// (row>>1)&3 (the proven rpos pattern for 64B-stride rows; R15's (row&3)
// made rows {0,4,8,12} alias one bank-quad -> 8-way read conflicts, 3.83M).
// gl16 q-swizzle, counted vmcnt(4), sibling-XCD grouping + T5 setprio.
// ---------------------------------------------------------------------------
__global__ __launch_bounds__(256, 4) void proj_all(const bf16* __restrict__ Xh,
                                                   const bf16* __restrict__ WT,
                                                   const float* __restrict__ bias_f,
                                                   bf16* __restrict__ Q,
                                                   bf16* __restrict__ K,
                                                   bf16* __restrict__ Vct)
{
    const int flat = blockIdx.x;          // 0..1727
    const int xcd  = flat & 7;
    const int rest = flat >> 3;           // 0..215
    const int tgrp = rest / 12;           // 0..17
    const int sib  = rest - tgrp * 12;    // 0..11
    const int t    = tgrp * 8 + xcd;      // 0..143
    const bool isV = sib < 4;
    int ny, z;
    if (isV) { ny = sib; z = 2; }
    else { const int s = sib - 4; z = s >> 2; ny = s & 3; }

    const int pb = t / 9;                // 0..15
    const int f0 = (t - pb * 9) * 128;
    const int plane = pb >> 3, b = pb & 7;
    const int n0 = ny * 128;
    const int tid = threadIdx.x, wv = tid >> 6, lane = tid & 63;
    const int wm = (wv >> 1) * 64, wn = (wv & 1) * 64;
    const size_t pbase = (size_t)pb * PSTRIDE;

    const bf16* Bh = WT + (size_t)z * 524288;
    const float* bias = bias_f + z * 512;

    __shared__ __align__(1024) bf16 SH[16384];   // 32 KB: 2 x (A 8KB | B 8KB)

    const int r4 = lane >> 2;         // row within 16-row chunk
    const int sl = lane & 3;          // dest slot (of 4 qwords/row)
    const int q  = sl ^ ((r4 >> 1) & 3);  // logical qword fetched (FIXED swizzle)
    const int r16 = lane & 15, cc = lane >> 4;
    const int rsw = (r16 >> 1) & 3;
    const int nn2 = lane & 15, rq = (lane >> 4) * 4;

    auto STAGE = [&](int buf, int kt) {
        char* base = (char*)SH + buf * 16384;
        #pragma unroll
        for (int c2 = 0; c2 < 2; ++c2) {
            const int chunk = wv * 2 + c2;            // 0..7
            const int row = chunk * 16 + r4;
            gl16(&Xh[pbase + ((size_t)((kt >> 3) + q) * FPAD + f0 + row) * 8],
                 base + chunk * 1024);
            gl16(&Bh[(size_t)(n0 + row) * 512 + kt + q * 8],
                 base + 8192 + chunk * 1024);
        }
    };

    f32x4 acc[4][4] = {};
    STAGE(0, 0);
    for (int it = 0; it < 16; ++it) {
        if (it < 15) {
            STAGE((it + 1) & 1, (it + 1) * 32);
            asm volatile("s_waitcnt vmcnt(4)" ::: "memory");   // current 4 landed
        } else {
            asm volatile("s_waitcnt vmcnt(0)" ::: "memory");
        }
        __builtin_amdgcn_s_barrier();
        __builtin_amdgcn_sched_barrier(0);

        const bf16* Ab = SH + (it & 1) * 8192;
        const bf16* Bb = Ab + 4096;
        __builtin_amdgcn_s_setprio(1);
        {
            short8 af[4], bfr[4];
            const int sa = (cc ^ rsw) * 8;
            #pragma unroll
            for (int i = 0; i < 4; ++i) {
                af[i]  = *(const short8*)&Ab[(wm + i * 16 + r16) * 32 + sa];
                bfr[i] = *(const short8*)&Bb[(wn + i * 16 + r16) * 32 + sa];
            }
            #pragma unroll
            for (int i = 0; i < 4; ++i)
                #pragma unroll
                for (int j = 0; j < 4; ++j)
                    acc[i][j] = MFMA16(af[i], bfr[j], acc[i][j]);
        }
        __builtin_amdgcn_s_setprio(0);
        asm volatile("s_waitcnt lgkmcnt(0)" ::: "memory");
        __builtin_amdgcn_s_barrier();      // reads done before buffer overwrite
    }

    if (!isV) {
        // ----- Q/K epilogue: pre-swizzled bf16 planes for att's gl16 -----
        bf16* dst = z == 0 ? Q : K;
        const size_t SPQ = (size_t)BB * FF * DD;
        #pragma unroll
        for (int i = 0; i < 4; ++i)
            #pragma unroll
            for (int j = 0; j < 4; ++j) {
                const int col = n0 + wn + j * 16 + nn2;
                #pragma unroll
                for (int r = 0; r < 4; ++r) {
                    const int f = f0 + wm + i * 16 + rq + r;
                    if (f < FF) {
                        float v = acc[i][j][r];
                        if (plane == 0 && f == 0) v += 2048.0f * bias[col];
                        const int swz = ((f >> 1) & 3) << 3;
                        dst[(size_t)plane * SPQ + ((size_t)(b * FF + f)) * 512 + (col ^ swz)] = f2b(v);
                    }
                }
            }
    } else {
        // ----- V epilogue: transpose via LDS (full 32KB), write Vct[b,n,g] -----
        bf16* T = SH;
        __syncthreads();
        #pragma unroll
        for (int i = 0; i < 4; ++i)
            #pragma unroll
            for (int j = 0; j < 4; ++j) {
                const int col_l = wn + j * 16 + nn2;
                #pragma unroll
                for (int r = 0; r < 4; ++r) {
                    const int row_l = wm + i * 16 + rq + r;
                    const int f = f0 + row_l;
                    float v = (f < FF) ? acc[i][j][r] : 0.f;
                    if (plane == 0 && f == 0) v += 2048.0f * bias[n0 + col_l];
                    T[col_l * 128 + (row_l ^ ((col_l & 15) << 3))] = f2b(v);
                }
            }
        __syncthreads();

        const int nl = tid >> 1, half = tid & 1;
        const size_t gbase = ((size_t)(b * 1024 + plane * 512 + n0 + nl)) * GP + f0;
        #pragma unroll
        for (int a = 0; a < 8; ++a) {
            const int fl = half * 64 + a * 8;
            if (f0 + fl < GP) {
                const short8 v8 = *(const short8*)&T[nl * 128 + (fl ^ ((nl & 15) << 3))];
                *(short8*)&Vct[gbase + fl] = v8;
            }
        }
    }
}

// ---------------------------------------------------------------------------
// att_mfma: plain bf16, 2 planes. 128f x 64g block, 4 waves, BK=64
// (2 half-tiles of 32k each; 16 barriers). 48KB LDS, 2 blocks/CU.
// R12/R14-measured-best form.
// ---------------------------------------------------------------------------
__global__ __launch_bounds__(256, 2) void att_mfma(const bf16* __restrict__ Asp,
                                                   const bf16* __restrict__ Bsp,
                                                   float* __restrict__ att)
{
    const size_t SP = (size_t)BB * FF * DD;
    const int flat = blockIdx.x;
    const int b    = flat & 7;
    const int slot = flat >> 3;          // 0..152
    const int grp  = slot / 51;          // 0..2
    const int rem  = slot % 51;
    const int g    = rem / 3;            // 0..16
    const int r3   = rem % 3;
    const int ft   = grp * 3 + r3;       // 0..8
    const int f0 = ft * 128, g0 = g * 64;

    const int tid = threadIdx.x;
    const int wv = tid >> 6, lane = tid & 63;
    const int wvf = wv >> 1, wvg = wv & 1;

    // A: 2 halves x 16KB | B: 2 halves x 8KB  = 48 KB
    __shared__ __align__(1024) char LB[49152];

    f32x4 accr[4][2] = {}; f32x4 acci[4][2] = {};

    const int r16 = lane & 15, cc = lane >> 4;
    const int rpos = (cc ^ ((r16 >> 1) & 3)) * 8;
    const size_t abase = (size_t)(b * FF + f0) * 512;
    const size_t bbase = (size_t)(b * FF + g0) * 512;
    const int lrow = lane >> 2;          // 0..15 within a 16-row chunk
    const int lcol = (lane & 3) * 8;     // element offset of this lane's 16B

    for (int kt = 0; kt < 512; kt += 64) {
        // A: 32 chunks (2 halves x 2 planes x 8 row-groups); 8 per wave
        #pragma unroll
        for (int c2 = 0; c2 < 8; ++c2) {
            const int chunk = wv * 8 + c2;            // 0..31
            const int half = chunk >> 4;
            const int pl = (chunk >> 3) & 1, rg = chunk & 7;
            const int row = rg * 16 + lrow;
            gl16(&Asp[(size_t)pl * SP + abase + (size_t)row * 512 + kt + half * 32 + lcol],
                 LB + half * 16384 + ((pl << 3) | rg) * 1024);
        }
        // B: 16 chunks (2 halves x 2 planes x 4 row-groups); 4 per wave
        #pragma unroll
        for (int c2 = 0; c2 < 4; ++c2) {
            const int chunk = wv * 4 + c2;            // 0..15
            const int half = chunk >> 3;
            const int pl = (chunk >> 2) & 1, rg = chunk & 3;
            const int row = rg * 16 + lrow;
            gl16(&Bsp[(size_t)pl * SP + bbase + (size_t)row * 512 + kt + half * 32 + lcol],
                 LB + 32768 + half * 8192 + ((pl << 2) | rg) * 1024);
        }
        __syncthreads();

        #pragma unroll
        for (int kk = 0; kk < 2; ++kk) {
            bf16 (*Al)[128][32] = (bf16(*)[128][32])(LB + kk * 16384);
            bf16 (*Bl)[64][32]  = (bf16(*)[64][32])(LB + 32768 + kk * 8192);
            short8 aA[4][2], bB[2][2], nb[2];
            #pragma unroll
            for (int i = 0; i < 4; ++i) {
                const int row = wvf * 64 + i * 16 + r16;
                #pragma unroll
                for (int pl = 0; pl < 2; ++pl)
                    aA[i][pl] = *(const short8*)&Al[pl][row][rpos];
            }
            #pragma unroll
            for (int j = 0; j < 2; ++j) {
                const int row = wvg * 32 + j * 16 + r16;
                #pragma unroll
                for (int pl = 0; pl < 2; ++pl)
                    bB[j][pl] = *(const short8*)&Bl[pl][row][rpos];
                nb[j] = neg8(bB[j][1]);
            }
            #pragma unroll
            for (int i = 0; i < 4; ++i)
                #pragma unroll
                for (int j = 0; j < 2; ++j) {
                    accr[i][j] = MFMA16(aA[i][0], bB[j][0], accr[i][j]);
                    accr[i][j] = MFMA16(aA[i][1], nb[j],    accr[i][j]);
                    acci[i][j] = MFMA16(aA[i][0], bB[j][1], acci[i][j]);
                    acci[i][j] = MFMA16(aA[i][1], bB[j][0], acci[i][j]);
                }
        }
        __syncthreads();
    }

    const int rq = (lane >> 4) * 4;
    #pragma unroll
    for (int i = 0; i < 4; ++i)
        #pragma unroll
        for (int j = 0; j < 2; ++j)
            #pragma unroll
            for (int r = 0; r < 4; ++r) {
                const int f = f0 + wvf * 64 + i * 16 + rq + r;
                const int gg = g0 + wvg * 32 + j * 16 + r16;
                if (f < FF && gg < FF) {
                    const float ar = accr[i][j][r];
                    const float ai = acci[i][j][r];
                    att[((size_t)(b * FF + f)) * FF + gg] = ATT_SCALE * sqrtf(ar * ar + ai * ai);
                }
            }
}

// ---------------------------------------------------------------------------
// softmax over g per (b,f) row; LDS-staged; exp stored back (single expf pass).
// ---------------------------------------------------------------------------
__global__ __launch_bounds__(256) void softmax_rows(const float* __restrict__ att,
                                                    bf16* __restrict__ att16)
{
    const int row = blockIdx.x;
    const float* p = att + (size_t)row * FF;
    bf16* q = att16 + (size_t)row * GP;
    const int tid = threadIdx.x;
    const int lane = tid & 63, wid = tid >> 6;
    __shared__ float srow[1028];
    __shared__ float red[4];

    float m = -1e30f;
    for (int i = tid; i < FF; i += 256) {
        const float v = p[i];
        srow[i] = v;
        m = fmaxf(m, v);
    }
    #pragma unroll
    for (int o = 32; o; o >>= 1) m = fmaxf(m, __shfl_down(m, o));
    if (lane == 0) red[wid] = m;
    __syncthreads();
    m = fmaxf(fmaxf(red[0], red[1]), fmaxf(red[2], red[3]));
    __syncthreads();

    float s = 0.f;
    for (int i = tid; i < FF; i += 256) {
        const float e = expf(srow[i] - m);
        srow[i] = e;                      // own indices only — no race
        s += e;
    }
    #pragma unroll
    for (int o = 32; o; o >>= 1) s += __shfl_down(s, o);
    if (lane == 0) red[wid] = s;
    __syncthreads();
    s = red[0] + red[1] + red[2] + red[3];
    const float inv = 1.f / s;
    for (int i = tid; i < GP; i += 256)
        q[i] = f2b(i < FF ? srow[i] * inv : 0.f);
}

// ---------------------------------------------------------------------------
// ctx_mfma: 128f x 64n block, 4 waves, BK=64, gl16 staging, 2-PHASE pipeline
// (dbuf 48KB, counted vmcnt(6)) + T5 setprio. OOB f-rows -> discarded rows.
// Writes out-GEMM-ready bf16 Csp, row = (plane*8+b)*FPAD + f.
// ---------------------------------------------------------------------------
__global__ __launch_bounds__(256, 2) void ctx_mfma(const bf16* __restrict__ att16,
                                                   const bf16* __restrict__ Vct,
                                                   bf16* __restrict__ Csp)
{
    const int flat = blockIdx.x;          // 1152 blocks
    const int b    = flat & 7;
    const int slot = flat >> 3;           // 0..143
    const int ft   = slot >> 4;           // 0..8
    const int nt   = slot & 15;           // 0..15
    const int f0 = ft * 128, n0 = nt * 64;

    const int tid = threadIdx.x;
    const int wv = tid >> 6, lane = tid & 63;
    const int wvf = wv >> 1, wvg = wv & 1;

    __shared__ __align__(1024) bf16 SH[24576];   // 48 KB: 2 x (A 16KB | B 8KB)

    f32x4 acc[4][2] = {};
    const int r8 = lane >> 3, sl = lane & 7, q = sl ^ r8;
    const int r16 = lane & 15, cc = lane >> 4;
    const int rs8 = r16 & 7;

    auto STAGE = [&](int buf, int kt) {
        char* base = (char*)SH + buf * 24576;
        #pragma unroll
        for (int c2 = 0; c2 < 4; ++c2) {
            const int chunk = wv * 4 + c2;        // 0..15
            const int row = chunk * 8 + r8;
            gl16(&att16[((size_t)(b * FF + f0 + row)) * GP + kt + q * 8],
                 base + chunk * 1024);
        }
        #pragma unroll
        for (int c2 = 0; c2 < 2; ++c2) {
            const int chunk = wv * 2 + c2;        // 0..7
            const int row = chunk * 8 + r8;
            gl16(&Vct[((size_t)(b * 1024 + n0 + row)) * GP + kt + q * 8],
                 base + 16384 + chunk * 1024);
        }
    };

    STAGE(0, 0);
    for (int it = 0; it < 17; ++it) {        // GP/64 = 17
        if (it < 16) {
            STAGE((it + 1) & 1, (it + 1) * 64);
            asm volatile("s_waitcnt vmcnt(6)" ::: "memory");
        } else {
            asm volatile("s_waitcnt vmcnt(0)" ::: "memory");
        }
        __builtin_amdgcn_s_barrier();
        __builtin_amdgcn_sched_barrier(0);

        const bf16* Ab = SH + (it & 1) * 12288;
        const bf16* Bb = Ab + 8192;
        __builtin_amdgcn_s_setprio(1);
        #pragma unroll
        for (int kk = 0; kk < 2; ++kk) {
            short8 aA[4], bB[2];
            const int sa = ((kk * 4 + cc) ^ rs8) * 8;
            #pragma unroll
            for (int i = 0; i < 4; ++i)
                aA[i] = *(const short8*)&Ab[(wvf * 64 + i * 16 + r16) * 64 + sa];
            #pragma unroll
            for (int j = 0; j < 2; ++j)
                bB[j] = *(const short8*)&Bb[(wvg * 32 + j * 16 + r16) * 64 + sa];
            #pragma unroll
            for (int i = 0; i < 4; ++i)
                #pragma unroll
                for (int j = 0; j < 2; ++j)
                    acc[i][j] = MFMA16(aA[i], bB[j], acc[i][j]);
        }
        __builtin_amdgcn_s_setprio(0);
        asm volatile("s_waitcnt lgkmcnt(0)" ::: "memory");
        __builtin_amdgcn_s_barrier();
    }

    const int rq = (lane >> 4) * 4;
    #pragma unroll
    for (int i = 0; i < 4; ++i)
        #pragma unroll
        for (int j = 0; j < 2; ++j)
            #pragma unroll
            for (int r = 0; r < 4; ++r) {
                const int f = f0 + wvf * 64 + i * 16 + rq + r;
                const int n = n0 + wvg * 32 + j * 16 + r16;
                if (f < FF) {
                    const int d = n & 511, pl = n >> 9;
                    Csp[((size_t)(pl * 8 + b) * FPAD + f) * 512 + d] = f2b(acc[i][j][r]);
                }
            }
}

// ---------------------------------------------------------------------------
// out_mfma_freq: Cw = Csp(bf16) @ WoT. 128x64 tiles (144x8 grid), BK=64,
// gl16 staging, 2-PHASE pipeline (dbuf 48KB, counted vmcnt(6)) + T5 setprio.
// ---------------------------------------------------------------------------
__global__ __launch_bounds__(256, 2) void out_mfma_freq(const bf16* __restrict__ A,
                                                        const bf16* __restrict__ BhT,
                                                        float* __restrict__ CwR,
                                                        float* __restrict__ CwI)
{
    const int t = blockIdx.x;            // 0..143
    const int pb = t / 9;
    const int f0 = (t - pb * 9) * 128;
    const int plane = pb >> 3, b = pb & 7;
    const int m0 = t * 128, n0 = blockIdx.y * 64;
    const int tid = threadIdx.x, wv = tid >> 6, lane = tid & 63;
    const int wvf = wv >> 1, wvg = wv & 1;

    __shared__ __align__(1024) bf16 SH[24576];   // 48 KB: 2 x (A 16KB | B 8KB)

    f32x4 acc[4][2] = {};
    const int r8 = lane >> 3, sl = lane & 7, q = sl ^ r8;
    const int r16 = lane & 15, cc = lane >> 4;
    const int rs8 = r16 & 7;

    auto STAGE = [&](int buf, int kt) {
        char* base = (char*)SH + buf * 24576;
        #pragma unroll
        for (int c2 = 0; c2 < 4; ++c2) {
            const int chunk = wv * 4 + c2;        // 0..15
            const int row = chunk * 8 + r8;
            gl16(&A[(size_t)(m0 + row) * 512 + kt + q * 8],
                 base + chunk * 1024);
        }
        #pragma unroll
        for (int c2 = 0; c2 < 2; ++c2) {
            const int chunk = wv * 2 + c2;        // 0..7
            const int row = chunk * 8 + r8;
            gl16(&BhT[(size_t)(n0 + row) * 512 + kt + q * 8],
                 base + 16384 + chunk * 1024);
        }
    };

    STAGE(0, 0);
    for (int it = 0; it < 8; ++it) {
        if (it < 7) {
            STAGE((it + 1) & 1, (it + 1) * 64);
            asm volatile("s_waitcnt vmcnt(6)" ::: "memory");
        } else {
            asm volatile("s_waitcnt vmcnt(0)" ::: "memory");
        }
        __builtin_amdgcn_s_barrier();
        __builtin_amdgcn_sched_barrier(0);

        const bf16* Ab = SH + (it & 1) * 12288;
        const bf16* Bb = Ab + 8192;
        __builtin_amdgcn_s_setprio(1);
        #pragma unroll
        for (int kk = 0; kk < 2; ++kk) {
            short8 af[4], bfr[2];
            const int sa = ((kk * 4 + cc) ^ rs8) * 8;
            #pragma unroll
            for (int i = 0; i < 4; ++i)
                af[i] = *(const short8*)&Ab[(wvf * 64 + i * 16 + r16) * 64 + sa];
            #pragma unroll
            for (int j = 0; j < 2; ++j)
                bfr[j] = *(const short8*)&Bb[(wvg * 32 + j * 16 + r16) * 64 + sa];
            #pragma unroll
            for (int i = 0; i < 4; ++i)
                #pragma unroll
                for (int j = 0; j < 2; ++j)
                    acc[i][j] = MFMA16(af[i], bfr[j], acc[i][j]);
        }
        __builtin_amdgcn_s_setprio(0);
        asm volatile("s_waitcnt lgkmcnt(0)" ::: "memory");
        __builtin_amdgcn_s_barrier();
    }

    float* dst = plane ? CwI : CwR;
    const int nn2 = lane & 15, rq = (lane >> 4) * 4;
    #pragma unroll
    for (int i = 0; i < 4; ++i)
        #pragma unroll
        for (int j = 0; j < 2; ++j) {
            const int col = n0 + wvg * 32 + j * 16 + nn2;
            #pragma unroll
            for (int r = 0; r < 4; ++r) {
                const int f = f0 + wvf * 64 + i * 16 + rq + r;
                if (f < FF)
                    dst[((size_t)(b * FF + f)) * 512 + col] = acc[i][j][r];
            }
        }
}

// ---------------------------------------------------------------------------
// irfft8: Cw planes -> time domain, + bo, writes d_out (flag dtype).
// ---------------------------------------------------------------------------
__global__ __launch_bounds__(512) void irfft8(const float* __restrict__ CwR,
                                              const float* __restrict__ CwI,
                                              void* __restrict__ out,
                                              const float* __restrict__ bias_f,
                                              const int* __restrict__ flag)
{
    int b, dp;
    fft_decode(blockIdx.x, b, dp);
    const int d0 = dp * 8;
    __shared__ float2 sh[8192];
    __shared__ float2 twl[2048];
    const int tid = threadIdx.x;
    const int c = tid & 3, fb = tid >> 2;

    // hermitian construct
    for (int it = 0; it < 9; ++it) {
        const int f = fb + 128 * it;
        if (f < FF) {
            const size_t off = ((size_t)(b * FF + f)) * 512 + d0 + 2 * c;
            const float2 vr = *(const float2*)(CwR + off);
            const float2 vi = *(const float2*)(CwI + off);
            float c1x = vr.x, c1y = vi.x, c2x = vr.y, c2y = vi.y;
            if (f == 0 || f == 1024) { c1y = 0.f; c2y = 0.f; }
            sh[shx(f, c)] = make_float2(c1x - c2y, c1y + c2x);
            if (f >= 1 && f <= 1023)
                sh[shx(2048 - f, c)] = make_float2(c1x + c2y, c2x - c1y);
        }
    }
    fill_twl(twl, tid);
    __syncthreads();

    // inverse DIF (conjugated twiddles: sw = -w.y)
    const int jb = fb;
    #pragma unroll
    for (int lsm = 10; lsm >= 0; --lsm) {
        const int m = 1 << lsm;
        const int base = 2048 - (m << 1);
        #pragma unroll
        for (int r = 0; r < 8; ++r) {
            const int j  = jb + 128 * r;
            const int k  = j & (m - 1);
            const int i1 = ((j & ~(m - 1)) << 1) | k;
            const int i2 = i1 + m;
            const float2 w = twl[base + k];
            const float cw = w.x, sw = -w.y;
            const float2 a  = sh[shx(i1, c)];
            const float2 bb = sh[shx(i2, c)];
            sh[shx(i1, c)] = make_float2(a.x + bb.x, a.y + bb.y);
            const float dx = a.x - bb.x, dy = a.y - bb.y;
            sh[shx(i2, c)] = make_float2(dx * cw - dy * sw, dx * sw + dy * cw);
        }
        __syncthreads();
    }

    // write + bo
    const float sc = 1.0f / 2048.0f;
    const float bo0 = bias_f[1536 + d0 + 2 * c];
    const float bo1 = bias_f[1536 + d0 + 2 * c + 1];
    const bool f32o = (*flag) != 0;
    const int lb = tid >> 2;
    #pragma unroll
    for (int it = 0; it < 16; ++it) {
        const int l  = lb * 16 + it;
        const int rl = __brev((unsigned)l) >> 21;
        const float2 z = sh[shx(rl, c)];
        const float o0 = z.x * sc + bo0;
        const float o1 = z.y * sc + bo1;
        const size_t off = ((size_t)(b * 2048 + l)) * 512 + d0 + 2 * c;
        if (f32o) {
            *(float2*)((float*)out + off) = make_float2(o0, o1);
        } else {
            __hip_bfloat162 h;
            h.x = f2b(o0); h.y = f2b(o1);
            *(__hip_bfloat162*)((bf16*)out + off) = h;
        }
    }
}

// ---------------------------------------------------------------------------
// launch — freq-domain pipeline, 9 dispatches.
// Regions:
//   A [0, 33.65MB):   attn (att out)
//   B [+37.75MB):     Xh (rfft_x out, panel layout) -> att16 | Csp
//   C [+17.04MB):     Asp -> CwR
//   D [+17.04MB):     Bsp -> CwI
//   E [+17.83MB):     Vct (8192 rows x GP=1088 x 2B = 17,825,792 exactly)
//   W [+4.2MB]:       WT, bias_f, flag
// ---------------------------------------------------------------------------
extern "C" void kernel_launch(void* const* d_in, const int* in_sizes, int n_in,
                              void* d_out, int out_size, void* d_ws, size_t ws_size,
                              hipStream_t stream)
{
    const void* x  = d_in[0];
    const void* Wq = d_in[1]; const void* bq = d_in[2];
    const void* Wk = d_in[3]; const void* bk = d_in[4];
    const void* Wv = d_in[5]; const void* bv = d_in[6];
    const void* Wo = d_in[7]; const void* bo = d_in[8];

    char* ws = (char*)d_ws;
    char* pA = ws;                          // 33,652,736
    char* pB = pA + 33652736;               // 37,748,736
    char* pC = pB + 37748736;               // 17,039,360
    char* pD = pC + 17039360;               // 17,039,360
    char* pE = pD + 17039360;               // 17,825,792
    char* pW = pE + 17825792;

    float*  attn = (float*)pA;
    bf16*   Xh   = (bf16*)pB;
    bf16*   att16= (bf16*)pB;                       // 8200*1088*2 = 17,843,200 B
    bf16*   Csp  = (bf16*)(pB + 17843200);          // + 18,874,368 <= region end
    bf16*   Asp  = (bf16*)pC;
    bf16*   Bsp  = (bf16*)pD;
    float*  CwR  = (float*)pC;
    float*  CwI  = (float*)pD;
    bf16*   Vct  = (bf16*)pE;
    bf16*   WT   = (bf16*)pW;
    float*  bias_f = (float*)(pW + 4194304);
    int*    flag = (int*)(pW + 4194304 + 8192);

    detect_dtype<<<1, 256, 0, stream>>>((const unsigned short*)x, flag);
    split_w_t<<<dim3(16, 16, 4), 256, 0, stream>>>(Wq, Wk, Wv, Wo, bq, bk, bv, bo,
                                                   WT, bias_f, flag);
    rfft_x<<<dim3(512), 512, 0, stream>>>(x, Xh, flag);
    proj_all<<<dim3(1728), 256, 0, stream>>>(Xh, WT, bias_f, Asp, Bsp, Vct);
    att_mfma<<<dim3(1224), 256, 0, stream>>>(Asp, Bsp, attn);
    softmax_rows<<<dim3(BB * FF), 256, 0, stream>>>(attn, att16);
    ctx_mfma<<<dim3(1152), 256, 0, stream>>>(att16, Vct, Csp);
    out_mfma_freq<<<dim3(144, 8), 256, 0, stream>>>(Csp, WT + 3 * 524288, CwR, CwI);
    irfft8<<<dim3(512), 512, 0, stream>>>(CwR, CwI, d_out, bias_f, flag);
}

// Round 17
// 295.961 us; speedup vs baseline: 1.1268x; 1.0541x over previous
//
#include <hip/hip_runtime.h>
#include <hip/hip_bf16.h>
#include <math.h>

typedef __hip_bfloat16 bf16;
typedef __attribute__((ext_vector_type(8))) short short8;
typedef __attribute__((ext_vector_type(4))) float f32x4;

#define BB 8
#define LL 2048
#define DD 512
#define FF 1025   // LL/2+1
#define GP 1088   // g padded to 17*64 for ctx BK=64 K-chunks
#define FPAD 1152 // freq rows padded per (plane,b): 9 tiles of 128
#define PSTRIDE 589824   // pb panel-block stride = 64*FPAD*8 elements
#define ATT_SCALE 0.04419417382415922f   // 512^-0.5

__device__ __forceinline__ float b2f(bf16 v) { return __bfloat162float(v); }
__device__ __forceinline__ bf16  f2b(float v) { return __float2bfloat16(v); }
__device__ __forceinline__ float s2f(short s) { bf16 t; *reinterpret_cast<short*>(&t) = s; return b2f(t); }
__device__ __forceinline__ unsigned pk2f(float a, float b) {
    bf16 ha = f2b(a), hb = f2b(b);
    return (unsigned)*(unsigned short*)&ha | ((unsigned)*(unsigned short*)&hb << 16);
}

#define MFMA16(a, b, c) __builtin_amdgcn_mfma_f32_16x16x32_bf16((a), (b), (c), 0, 0, 0)

// exact bf16 negation of an 8-element fragment (sign-bit flip)
__device__ __forceinline__ short8 neg8(short8 v) {
    short8 r;
    #pragma unroll
    for (int t = 0; t < 8; ++t) r[t] = (short)(v[t] ^ (short)0x8000);
    return r;
}

// async global->LDS: 16B per lane, dest = wave-uniform base + lane*16 (linear)
typedef __attribute__((address_space(1))) const unsigned int gu32;
typedef __attribute__((address_space(3))) unsigned int lu32;
__device__ __forceinline__ void gl16(const void* g, void* l) {
    __builtin_amdgcn_global_load_lds((gu32*)g, (lu32*)l, 16, 0, 0);
}

template<bool F32>
__device__ __forceinline__ float ldin(const void* p, size_t i) {
    if (F32) return ((const float*)p)[i];
    else     return b2f(((const bf16*)p)[i]);
}

// ---------------------------------------------------------------------------
// dtype detector (flag: 1 = fp32 inputs, 0 = bf16).
// ---------------------------------------------------------------------------
__global__ __launch_bounds__(256) void detect_dtype(const unsigned short* __restrict__ x,
                                                    int* __restrict__ flag)
{
    __shared__ int cnt[256];
    int c = 0;
    for (int i = threadIdx.x; i < 4096; i += 256) {
        const int e = (x[i] >> 7) & 0xFF;
        c += (e >= 100 && e <= 150) ? 1 : 0;
    }
    cnt[threadIdx.x] = c;
    __syncthreads();
    for (int s = 128; s; s >>= 1) {
        if (threadIdx.x < s) cnt[threadIdx.x] += cnt[threadIdx.x + s];
        __syncthreads();
    }
    if (threadIdx.x == 0) *flag = (cnt[0] < 3400) ? 1 : 0;
}

// ---------------------------------------------------------------------------
// split_w_t (+ fused bias prep): W[512,512] -> transposed bf16 plane WT[n][k];
// block (0,0,z) also writes bias_f[z*512..].
// ---------------------------------------------------------------------------
__global__ __launch_bounds__(256) void split_w_t(const void* __restrict__ W0,
                                                 const void* __restrict__ W1,
                                                 const void* __restrict__ W2,
                                                 const void* __restrict__ W3,
                                                 const void* __restrict__ b0,
                                                 const void* __restrict__ b1,
                                                 const void* __restrict__ b2,
                                                 const void* __restrict__ b3,
                                                 bf16* __restrict__ WT,
                                                 float* __restrict__ bias_f,
                                                 const int* __restrict__ flag)
{
    const int z = blockIdx.z;
    const void* W = z == 0 ? W0 : (z == 1 ? W1 : (z == 2 ? W2 : W3));
    bf16* Wh = WT + (size_t)z * 524288;
    const int k0 = blockIdx.x * 32, n0 = blockIdx.y * 32;
    const bool f32 = (*flag) != 0;
    __shared__ float Tl[32][33];
    for (int it = 0; it < 4; ++it) {
        const int idx = it * 256 + threadIdx.x;
        const int lk = idx >> 5, ln = idx & 31;
        Tl[lk][ln] = f32 ? ldin<true>(W, (size_t)(k0 + lk) * 512 + n0 + ln)
                         : ldin<false>(W, (size_t)(k0 + lk) * 512 + n0 + ln);
    }
    __syncthreads();
    for (int it = 0; it < 4; ++it) {
        const int idx = it * 256 + threadIdx.x;
        const int ln = idx >> 5, lk = idx & 31;
        Wh[(size_t)(n0 + ln) * 512 + k0 + lk] = f2b(Tl[lk][ln]);
    }
    if (blockIdx.x == 0 && blockIdx.y == 0) {
        const void* bsrc = z == 0 ? b0 : (z == 1 ? b1 : (z == 2 ? b2 : b3));
        for (int i = threadIdx.x; i < 512; i += 256)
            bias_f[z * 512 + i] = f32 ? ldin<true>(bsrc, i) : ldin<false>(bsrc, i);
    }
}

// ===========================================================================
// 8-column FFT machinery.
// ===========================================================================
__device__ __forceinline__ int shx(int i, int c) {
    const int x = (i << 2) | c;
    return x ^ (((x >> 6) & 3) << 2);
}

// XCD-paired flat-grid decode.
__device__ __forceinline__ void fft_decode(int flat, int& b, int& dp) {
    const int c8 = flat & 7;
    const int s  = (flat >> 3) & 1;
    const int pp = flat >> 4;            // 0..31
    const int idx = c8 * 32 + pp;        // 0..255
    b  = idx >> 5;
    dp = ((idx & 31) << 1) | s;          // 0..63
}

// Per-stage-PACKED twiddle table: stage m's entries at [2048-2m, 2048-2m+m).
__device__ __forceinline__ void fill_twl(float2* twl, int tid) {
    for (int idx = tid; idx < 2047; idx += 512) {
        const int l2 = 31 - __builtin_clz((unsigned)(2047 - idx));
        const int m = 1 << l2;
        const int k = idx - 2048 + 2 * m;
        float s, c2;
        __sincosf(-3.14159265358979f * (float)k / (float)m, &s, &c2);
        twl[idx] = make_float2(c2, s);
    }
}

// Fused 2-stage DIF loop (stages (lsm,lsm-1) pairs + trivial stage 0).
// Bit-identical FP ops vs the unfused radix-2 sequence; halves LDS traffic
// and barriers (11 -> 6). INV=conjugated twiddles for inverse transform.
template<bool INV>
__device__ __forceinline__ void dif2048(float2* sh, const float2* twl,
                                        int jb, int c)
{
    #pragma unroll
    for (int lsm = 10; lsm >= 2; lsm -= 2) {
        const int mh = 1 << (lsm - 1);
        const int baseM  = 2048 - (2 << lsm);
        const int baseM2 = 2048 - (1 << lsm);
        #pragma unroll
        for (int r = 0; r < 4; ++r) {
            const int g = jb + 128 * r;            // 0..511
            const int k = g & (mh - 1);
            const int base = ((g & ~(mh - 1)) << 2) | k;
            const int p0 = base, p1 = base + mh, p2 = base + 2 * mh, p3 = base + 3 * mh;
            float2 w0 = twl[baseM + k];
            float2 w1 = twl[baseM + k + mh];
            float2 w2 = twl[baseM2 + k];
            if (INV) { w0.y = -w0.y; w1.y = -w1.y; w2.y = -w2.y; }
            const float2 x0 = sh[shx(p0, c)], x1 = sh[shx(p1, c)];
            const float2 x2 = sh[shx(p2, c)], x3 = sh[shx(p3, c)];
            // stage m
            const float2 u0 = make_float2(x0.x + x2.x, x0.y + x2.y);
            float dx = x0.x - x2.x, dy = x0.y - x2.y;
            const float2 u2 = make_float2(dx * w0.x - dy * w0.y, dx * w0.y + dy * w0.x);
            const float2 u1 = make_float2(x1.x + x3.x, x1.y + x3.y);
            dx = x1.x - x3.x; dy = x1.y - x3.y;
            const float2 u3 = make_float2(dx * w1.x - dy * w1.y, dx * w1.y + dy * w1.x);
            // stage m/2
            const float2 v0 = make_float2(u0.x + u1.x, u0.y + u1.y);
            dx = u0.x - u1.x; dy = u0.y - u1.y;
            const float2 v1 = make_float2(dx * w2.x - dy * w2.y, dx * w2.y + dy * w2.x);
            const float2 v2 = make_float2(u2.x + u3.x, u2.y + u3.y);
            dx = u2.x - u3.x; dy = u2.y - u3.y;
            const float2 v3 = make_float2(dx * w2.x - dy * w2.y, dx * w2.y + dy * w2.x);
            sh[shx(p0, c)] = v0; sh[shx(p1, c)] = v1;
            sh[shx(p2, c)] = v2; sh[shx(p3, c)] = v3;
        }
        __syncthreads();
    }
    // final stage (m=1, w=1): (a+b, a-b)
    #pragma unroll
    for (int r = 0; r < 8; ++r) {
        const int j = jb + 128 * r;                // 0..1023
        const int i1 = j << 1, i2 = i1 + 1;
        const float2 a = sh[shx(i1, c)], bb = sh[shx(i2, c)];
        sh[shx(i1, c)] = make_float2(a.x + bb.x, a.y + bb.y);
        sh[shx(i2, c)] = make_float2(a.x - bb.x, a.y - bb.y);
    }
    __syncthreads();
}

// rfft on x: x[b,l,d] -> Xh bf16 PANEL layout:
// panel = plane*512 + b*64 + dp ; addr = (panel*FPAD + f)*8 + (d&7).
__global__ __launch_bounds__(512) void rfft_x(const void* __restrict__ x,
                                              bf16* __restrict__ Xh,
                                              const int* __restrict__ flag)
{
    int b, dp;
    fft_decode(blockIdx.x, b, dp);
    const int d0 = dp * 8;
    __shared__ float2 sh[8192];          // 64 KB
    __shared__ float2 twl[2048];         // 16 KB packed twiddles
    const int tid = threadIdx.x;
    const int c = tid & 3;

    if (*flag) {
        const float* base = (const float*)x + (size_t)b * 2048 * 512 + d0;
        #pragma unroll
        for (int it = 0; it < 8; ++it) {
            const int idx = it * 512 + tid;          // 0..4095
            const int l = idx >> 1, fq = idx & 1;
            const float4 v = *(const float4*)(base + (size_t)l * 512 + fq * 4);
            sh[shx(l, fq * 2)]     = make_float2(v.x, v.y);
            sh[shx(l, fq * 2 + 1)] = make_float2(v.z, v.w);
        }
    } else {
        const bf16* base = (const bf16*)x + (size_t)b * 2048 * 512 + d0;
        #pragma unroll
        for (int it = 0; it < 4; ++it) {
            const int l = it * 512 + tid;
            const short8 v = *(const short8*)(base + (size_t)l * 512);
            #pragma unroll
            for (int q = 0; q < 4; ++q)
                sh[shx(l, q)] = make_float2(s2f(v[2 * q]), s2f(v[2 * q + 1]));
        }
    }
    fill_twl(twl, tid);
    __syncthreads();

    dif2048<false>(sh, twl, tid >> 2, c);

    // unpack 2-real-signals + bf16 PANEL writes
    const int fb = tid >> 2;
    const size_t pan_re = (size_t)(b * 64 + dp) * FPAD;        // row base (re)
    const size_t pan_im = pan_re + (size_t)512 * FPAD;         // +plane stride
    auto dorow = [&](int f) {
        const int rf = __brev((unsigned)f) >> 21;
        const int rc = __brev((unsigned)((2048 - f) & 2047)) >> 21;
        const float2 Zf = sh[shx(rf, c)];
        const float2 Zc = sh[shx(rc, c)];
        const float x1r = 0.5f * (Zf.x + Zc.x);
        const float x1i = 0.5f * (Zf.y - Zc.y);
        const float x2r = 0.5f * (Zf.y + Zc.y);
        const float x2i = -0.5f * (Zf.x - Zc.x);
        const size_t ro_re = (pan_re + f) * 8 + 2 * c;
        const size_t ro_im = (pan_im + f) * 8 + 2 * c;
        *(unsigned*)&Xh[ro_re] = pk2f(x1r, x2r);
        *(unsigned*)&Xh[ro_im] = pk2f(x1i, x2i);
    };
    #pragma unroll
    for (int it = 0; it < 8; ++it)
        dorow(fb * 8 + it);
    if (tid < 4) dorow(1024);

    // zero pad rows f in [FF, FPAD) for this panel (both planes)
    if (tid < 254) {
        const int f = FF + (tid >> 1);
        const int w = tid & 1;            // 0: re plane, 1: im plane
        const size_t off = (((size_t)(w * 512 + b * 64 + dp)) * FPAD + f) * 8;
        short8 z = {};
        *(short8*)&Xh[off] = z;
    }
}

// ---------------------------------------------------------------------------
// proj_all: ONE dispatch, uniform plain-bf16 GEMM, BK=32 2-PHASE pipeline
// (dbuf 32KB, ~4 blocks/CU), gl16 q-swizzle ((row>>1)&3, R16-verified),
// counted vmcnt(4), sibling-XCD grouping + T5 setprio.
// ---------------------------------------------------------------------------
__global__ __launch_bounds__(256, 4) void proj_all(const bf16* __restrict__ Xh,
                                                   const bf16* __restrict__ WT,
                                                   const float* __restrict__ bias_f,
                                                   bf16* __restrict__ Q,
                                                   bf16* __restrict__ K,
                                                   bf16* __restrict__ Vct)
{
    const int flat = blockIdx.x;          // 0..1727
    const int xcd  = flat & 7;
    const int rest = flat >> 3;           // 0..215
    const int tgrp = rest / 12;           // 0..17
    const int sib  = rest - tgrp * 12;    // 0..11
    const int t    = tgrp * 8 + xcd;      // 0..143
    const bool isV = sib < 4;
    int ny, z;
    if (isV) { ny = sib; z = 2; }
    else { const int s = sib - 4; z = s >> 2; ny = s & 3; }

    const int pb = t / 9;                // 0..15
    const int f0 = (t - pb * 9) * 128;
    const int plane = pb >> 3, b = pb & 7;
    const int n0 = ny * 128;
    const int tid = threadIdx.x, wv = tid >> 6, lane = tid & 63;
    const int wm = (wv >> 1) * 64, wn = (wv & 1) * 64;
    const size_t pbase = (size_t)pb * PSTRIDE;

    const bf16* Bh = WT + (size_t)z * 524288;
    const float* bias = bias_f + z * 512;

    __shared__ __align__(1024) bf16 SH[16384];   // 32 KB: 2 x (A 8KB | B 8KB)

    const int r4 = lane >> 2;         // row within 16-row chunk
    const int sl = lane & 3;          // dest slot (of 4 qwords/row)
    const int q  = sl ^ ((r4 >> 1) & 3);  // logical qword fetched
    const int r16 = lane & 15, cc = lane >> 4;
    const int rsw = (r16 >> 1) & 3;
    const int nn2 = lane & 15, rq = (lane >> 4) * 4;

    auto STAGE = [&](int buf, int kt) {
        char* base = (char*)SH + buf * 16384;
        #pragma unroll
        for (int c2 = 0; c2 < 2; ++c2) {
            const int chunk = wv * 2 + c2;            // 0..7
            const int row = chunk * 16 + r4;
            gl16(&Xh[pbase + ((size_t)((kt >> 3) + q) * FPAD + f0 + row) * 8],
                 base + chunk * 1024);
            gl16(&Bh[(size_t)(n0 + row) * 512 + kt + q * 8],
                 base + 8192 + chunk * 1024);
        }
    };

    f32x4 acc[4][4] = {};
    STAGE(0, 0);
    for (int it = 0; it < 16; ++it) {
        if (it < 15) {
            STAGE((it + 1) & 1, (it + 1) * 32);
            asm volatile("s_waitcnt vmcnt(4)" ::: "memory");   // current 4 landed
        } else {
            asm volatile("s_waitcnt vmcnt(0)" ::: "memory");
        }
        __builtin_amdgcn_s_barrier();
        __builtin_amdgcn_sched_barrier(0);

        const bf16* Ab = SH + (it & 1) * 8192;
        const bf16* Bb = Ab + 4096;
        __builtin_amdgcn_s_setprio(1);
        {
            short8 af[4], bfr[4];
            const int sa = (cc ^ rsw) * 8;
            #pragma unroll
            for (int i = 0; i < 4; ++i) {
                af[i]  = *(const short8*)&Ab[(wm + i * 16 + r16) * 32 + sa];
                bfr[i] = *(const short8*)&Bb[(wn + i * 16 + r16) * 32 + sa];
            }
            #pragma unroll
            for (int i = 0; i < 4; ++i)
                #pragma unroll
                for (int j = 0; j < 4; ++j)
                    acc[i][j] = MFMA16(af[i], bfr[j], acc[i][j]);
        }
        __builtin_amdgcn_s_setprio(0);
        asm volatile("s_waitcnt lgkmcnt(0)" ::: "memory");
        __builtin_amdgcn_s_barrier();      // reads done before buffer overwrite
    }

    if (!isV) {
        // ----- Q/K epilogue: pre-swizzled bf16 planes for att's gl16 -----
        bf16* dst = z == 0 ? Q : K;
        const size_t SPQ = (size_t)BB * FF * DD;
        #pragma unroll
        for (int i = 0; i < 4; ++i)
            #pragma unroll
            for (int j = 0; j < 4; ++j) {
                const int col = n0 + wn + j * 16 + nn2;
                #pragma unroll
                for (int r = 0; r < 4; ++r) {
                    const int f = f0 + wm + i * 16 + rq + r;
                    if (f < FF) {
                        float v = acc[i][j][r];
                        if (plane == 0 && f == 0) v += 2048.0f * bias[col];
                        const int swz = ((f >> 1) & 3) << 3;
                        dst[(size_t)plane * SPQ + ((size_t)(b * FF + f)) * 512 + (col ^ swz)] = f2b(v);
                    }
                }
            }
    } else {
        // ----- V epilogue: transpose via LDS (full 32KB), write Vct[b,n,g] -----
        bf16* T = SH;
        __syncthreads();
        #pragma unroll
        for (int i = 0; i < 4; ++i)
            #pragma unroll
            for (int j = 0; j < 4; ++j) {
                const int col_l = wn + j * 16 + nn2;
                #pragma unroll
                for (int r = 0; r < 4; ++r) {
                    const int row_l = wm + i * 16 + rq + r;
                    const int f = f0 + row_l;
                    float v = (f < FF) ? acc[i][j][r] : 0.f;
                    if (plane == 0 && f == 0) v += 2048.0f * bias[n0 + col_l];
                    T[col_l * 128 + (row_l ^ ((col_l & 15) << 3))] = f2b(v);
                }
            }
        __syncthreads();

        const int nl = tid >> 1, half = tid & 1;
        const size_t gbase = ((size_t)(b * 1024 + plane * 512 + n0 + nl)) * GP + f0;
        #pragma unroll
        for (int a = 0; a < 8; ++a) {
            const int fl = half * 64 + a * 8;
            if (f0 + fl < GP) {
                const short8 v8 = *(const short8*)&T[nl * 128 + (fl ^ ((nl & 15) << 3))];
                *(short8*)&Vct[gbase + fl] = v8;
            }
        }
    }
}

// ---------------------------------------------------------------------------
// att_mfma: plain bf16, 2 planes. 128f x 64g block, 4 waves, BK=64
// (2 half-tiles of 32k each; 16 barriers). 48KB LDS, 2 blocks/CU.
// R12/R14-measured-best form.
// ---------------------------------------------------------------------------
__global__ __launch_bounds__(256, 2) void att_mfma(const bf16* __restrict__ Asp,
                                                   const bf16* __restrict__ Bsp,
                                                   float* __restrict__ att)
{
    const size_t SP = (size_t)BB * FF * DD;
    const int flat = blockIdx.x;
    const int b    = flat & 7;
    const int slot = flat >> 3;          // 0..152
    const int grp  = slot / 51;          // 0..2
    const int rem  = slot % 51;
    const int g    = rem / 3;            // 0..16
    const int r3   = rem % 3;
    const int ft   = grp * 3 + r3;       // 0..8
    const int f0 = ft * 128, g0 = g * 64;

    const int tid = threadIdx.x;
    const int wv = tid >> 6, lane = tid & 63;
    const int wvf = wv >> 1, wvg = wv & 1;

    // A: 2 halves x 16KB | B: 2 halves x 8KB  = 48 KB
    __shared__ __align__(1024) char LB[49152];

    f32x4 accr[4][2] = {}; f32x4 acci[4][2] = {};

    const int r16 = lane & 15, cc = lane >> 4;
    const int rpos = (cc ^ ((r16 >> 1) & 3)) * 8;
    const size_t abase = (size_t)(b * FF + f0) * 512;
    const size_t bbase = (size_t)(b * FF + g0) * 512;
    const int lrow = lane >> 2;          // 0..15 within a 16-row chunk
    const int lcol = (lane & 3) * 8;     // element offset of this lane's 16B

    for (int kt = 0; kt < 512; kt += 64) {
        // A: 32 chunks (2 halves x 2 planes x 8 row-groups); 8 per wave
        #pragma unroll
        for (int c2 = 0; c2 < 8; ++c2) {
            const int chunk = wv * 8 + c2;            // 0..31
            const int half = chunk >> 4;
            const int pl = (chunk >> 3) & 1, rg = chunk & 7;
            const int row = rg * 16 + lrow;
            gl16(&Asp[(size_t)pl * SP + abase + (size_t)row * 512 + kt + half * 32 + lcol],
                 LB + half * 16384 + ((pl << 3) | rg) * 1024);
        }
        // B: 16 chunks (2 halves x 2 planes x 4 row-groups); 4 per wave
        #pragma unroll
        for (int c2 = 0; c2 < 4; ++c2) {
            const int chunk = wv * 4 + c2;            // 0..15
            const int half = chunk >> 3;
            const int pl = (chunk >> 2) & 1, rg = chunk & 3;
            const int row = rg * 16 + lrow;
            gl16(&Bsp[(size_t)pl * SP + bbase + (size_t)row * 512 + kt + half * 32 + lcol],
                 LB + 32768 + half * 8192 + ((pl << 2) | rg) * 1024);
        }
        __syncthreads();

        #pragma unroll
        for (int kk = 0; kk < 2; ++kk) {
            bf16 (*Al)[128][32] = (bf16(*)[128][32])(LB + kk * 16384);
            bf16 (*Bl)[64][32]  = (bf16(*)[64][32])(LB + 32768 + kk * 8192);
            short8 aA[4][2], bB[2][2], nb[2];
            #pragma unroll
            for (int i = 0; i < 4; ++i) {
                const int row = wvf * 64 + i * 16 + r16;
                #pragma unroll
                for (int pl = 0; pl < 2; ++pl)
                    aA[i][pl] = *(const short8*)&Al[pl][row][rpos];
            }
            #pragma unroll
            for (int j = 0; j < 2; ++j) {
                const int row = wvg * 32 + j * 16 + r16;
                #pragma unroll
                for (int pl = 0; pl < 2; ++pl)
                    bB[j][pl] = *(const short8*)&Bl[pl][row][rpos];
                nb[j] = neg8(bB[j][1]);
            }
            #pragma unroll
            for (int i = 0; i < 4; ++i)
                #pragma unroll
                for (int j = 0; j < 2; ++j) {
                    accr[i][j] = MFMA16(aA[i][0], bB[j][0], accr[i][j]);
                    accr[i][j] = MFMA16(aA[i][1], nb[j],    accr[i][j]);
                    acci[i][j] = MFMA16(aA[i][0], bB[j][1], acci[i][j]);
                    acci[i][j] = MFMA16(aA[i][1], bB[j][0], acci[i][j]);
                }
        }
        __syncthreads();
    }

    const int rq = (lane >> 4) * 4;
    #pragma unroll
    for (int i = 0; i < 4; ++i)
        #pragma unroll
        for (int j = 0; j < 2; ++j)
            #pragma unroll
            for (int r = 0; r < 4; ++r) {
                const int f = f0 + wvf * 64 + i * 16 + rq + r;
                const int gg = g0 + wvg * 32 + j * 16 + r16;
                if (f < FF && gg < FF) {
                    const float ar = accr[i][j][r];
                    const float ai = acci[i][j][r];
                    att[((size_t)(b * FF + f)) * FF + gg] = ATT_SCALE * sqrtf(ar * ar + ai * ai);
                }
            }
}

// ---------------------------------------------------------------------------
// softmax over g per (b,f) row; LDS-staged; exp stored back (single expf pass).
// ---------------------------------------------------------------------------
__global__ __launch_bounds__(256) void softmax_rows(const float* __restrict__ att,
                                                    bf16* __restrict__ att16)
{
    const int row = blockIdx.x;
    const float* p = att + (size_t)row * FF;
    bf16* q = att16 + (size_t)row * GP;
    const int tid = threadIdx.x;
    const int lane = tid & 63, wid = tid >> 6;
    __shared__ float srow[1028];
    __shared__ float red[4];

    float m = -1e30f;
    for (int i = tid; i < FF; i += 256) {
        const float v = p[i];
        srow[i] = v;
        m = fmaxf(m, v);
    }
    #pragma unroll
    for (int o = 32; o; o >>= 1) m = fmaxf(m, __shfl_down(m, o));
    if (lane == 0) red[wid] = m;
    __syncthreads();
    m = fmaxf(fmaxf(red[0], red[1]), fmaxf(red[2], red[3]));
    __syncthreads();

    float s = 0.f;
    for (int i = tid; i < FF; i += 256) {
        const float e = expf(srow[i] - m);
        srow[i] = e;                      // own indices only — no race
        s += e;
    }
    #pragma unroll
    for (int o = 32; o; o >>= 1) s += __shfl_down(s, o);
    if (lane == 0) red[wid] = s;
    __syncthreads();
    s = red[0] + red[1] + red[2] + red[3];
    const float inv = 1.f / s;
    for (int i = tid; i < GP; i += 256)
        q[i] = f2b(i < FF ? srow[i] * inv : 0.f);
}

// ---------------------------------------------------------------------------
// ctx_mfma: 128f x 64n block, 4 waves, BK=64, gl16 staging, 2-PHASE pipeline
// (dbuf 48KB, counted vmcnt(6)) + T5 setprio. OOB f-rows -> discarded rows.
// Writes out-GEMM-ready bf16 Csp, row = (plane*8+b)*FPAD + f.
// ---------------------------------------------------------------------------
__global__ __launch_bounds__(256, 2) void ctx_mfma(const bf16* __restrict__ att16,
                                                   const bf16* __restrict__ Vct,
                                                   bf16* __restrict__ Csp)
{
    const int flat = blockIdx.x;          // 1152 blocks
    const int b    = flat & 7;
    const int slot = flat >> 3;           // 0..143
    const int ft   = slot >> 4;           // 0..8
    const int nt   = slot & 15;           // 0..15
    const int f0 = ft * 128, n0 = nt * 64;

    const int tid = threadIdx.x;
    const int wv = tid >> 6, lane = tid & 63;
    const int wvf = wv >> 1, wvg = wv & 1;

    __shared__ __align__(1024) bf16 SH[24576];   // 48 KB: 2 x (A 16KB | B 8KB)

    f32x4 acc[4][2] = {};
    const int r8 = lane >> 3, sl = lane & 7, q = sl ^ r8;
    const int r16 = lane & 15, cc = lane >> 4;
    const int rs8 = r16 & 7;

    auto STAGE = [&](int buf, int kt) {
        char* base = (char*)SH + buf * 24576;
        #pragma unroll
        for (int c2 = 0; c2 < 4; ++c2) {
            const int chunk = wv * 4 + c2;        // 0..15
            const int row = chunk * 8 + r8;
            gl16(&att16[((size_t)(b * FF + f0 + row)) * GP + kt + q * 8],
                 base + chunk * 1024);
        }
        #pragma unroll
        for (int c2 = 0; c2 < 2; ++c2) {
            const int chunk = wv * 2 + c2;        // 0..7
            const int row = chunk * 8 + r8;
            gl16(&Vct[((size_t)(b * 1024 + n0 + row)) * GP + kt + q * 8],
                 base + 16384 + chunk * 1024);
        }
    };

    STAGE(0, 0);
    for (int it = 0; it < 17; ++it) {        // GP/64 = 17
        if (it < 16) {
            STAGE((it + 1) & 1, (it + 1) * 64);
            asm volatile("s_waitcnt vmcnt(6)" ::: "memory");
        } else {
            asm volatile("s_waitcnt vmcnt(0)" ::: "memory");
        }
        __builtin_amdgcn_s_barrier();
        __builtin_amdgcn_sched_barrier(0);

        const bf16* Ab = SH + (it & 1) * 12288;
        const bf16* Bb = Ab + 8192;
        __builtin_amdgcn_s_setprio(1);
        #pragma unroll
        for (int kk = 0; kk < 2; ++kk) {
            short8 aA[4], bB[2];
            const int sa = ((kk * 4 + cc) ^ rs8) * 8;
            #pragma unroll
            for (int i = 0; i < 4; ++i)
                aA[i] = *(const short8*)&Ab[(wvf * 64 + i * 16 + r16) * 64 + sa];
            #pragma unroll
            for (int j = 0; j < 2; ++j)
                bB[j] = *(const short8*)&Bb[(wvg * 32 + j * 16 + r16) * 64 + sa];
            #pragma unroll
            for (int i = 0; i < 4; ++i)
                #pragma unroll
                for (int j = 0; j < 2; ++j)
                    acc[i][j] = MFMA16(aA[i], bB[j], acc[i][j]);
        }
        __builtin_amdgcn_s_setprio(0);
        asm volatile("s_waitcnt lgkmcnt(0)" ::: "memory");
        __builtin_amdgcn_s_barrier();
    }

    const int rq = (lane >> 4) * 4;
    #pragma unroll
    for (int i = 0; i < 4; ++i)
        #pragma unroll
        for (int j = 0; j < 2; ++j)
            #pragma unroll
            for (int r = 0; r < 4; ++r) {
                const int f = f0 + wvf * 64 + i * 16 + rq + r;
                const int n = n0 + wvg * 32 + j * 16 + r16;
                if (f < FF) {
                    const int d = n & 511, pl = n >> 9;
                    Csp[((size_t)(pl * 8 + b) * FPAD + f) * 512 + d] = f2b(acc[i][j][r]);
                }
            }
}

// ---------------------------------------------------------------------------
// out_mfma_freq: Cw = Csp(bf16) @ WoT. 128x64 tiles (144x8 grid), BK=64,
// gl16 staging, 2-PHASE pipeline (dbuf 48KB, counted vmcnt(6)) + T5 setprio.
// ---------------------------------------------------------------------------
__global__ __launch_bounds__(256, 2) void out_mfma_freq(const bf16* __restrict__ A,
                                                        const bf16* __restrict__ BhT,
                                                        float* __restrict__ CwR,
                                                        float* __restrict__ CwI)
{
    const int t = blockIdx.x;            // 0..143
    const int pb = t / 9;
    const int f0 = (t - pb * 9) * 128;
    const int plane = pb >> 3, b = pb & 7;
    const int m0 = t * 128, n0 = blockIdx.y * 64;
    const int tid = threadIdx.x, wv = tid >> 6, lane = tid & 63;
    const int wvf = wv >> 1, wvg = wv & 1;

    __shared__ __align__(1024) bf16 SH[24576];   // 48 KB: 2 x (A 16KB | B 8KB)

    f32x4 acc[4][2] = {};
    const int r8 = lane >> 3, sl = lane & 7, q = sl ^ r8;
    const int r16 = lane & 15, cc = lane >> 4;
    const int rs8 = r16 & 7;

    auto STAGE = [&](int buf, int kt) {
        char* base = (char*)SH + buf * 24576;
        #pragma unroll
        for (int c2 = 0; c2 < 4; ++c2) {
            const int chunk = wv * 4 + c2;        // 0..15
            const int row = chunk * 8 + r8;
            gl16(&A[(size_t)(m0 + row) * 512 + kt + q * 8],
                 base + chunk * 1024);
        }
        #pragma unroll
        for (int c2 = 0; c2 < 2; ++c2) {
            const int chunk = wv * 2 + c2;        // 0..7
            const int row = chunk * 8 + r8;
            gl16(&BhT[(size_t)(n0 + row) * 512 + kt + q * 8],
                 base + 16384 + chunk * 1024);
        }
    };

    STAGE(0, 0);
    for (int it = 0; it < 8; ++it) {
        if (it < 7) {
            STAGE((it + 1) & 1, (it + 1) * 64);
            asm volatile("s_waitcnt vmcnt(6)" ::: "memory");
        } else {
            asm volatile("s_waitcnt vmcnt(0)" ::: "memory");
        }
        __builtin_amdgcn_s_barrier();
        __builtin_amdgcn_sched_barrier(0);

        const bf16* Ab = SH + (it & 1) * 12288;
        const bf16* Bb = Ab + 8192;
        __builtin_amdgcn_s_setprio(1);
        #pragma unroll
        for (int kk = 0; kk < 2; ++kk) {
            short8 af[4], bfr[2];
            const int sa = ((kk * 4 + cc) ^ rs8) * 8;
            #pragma unroll
            for (int i = 0; i < 4; ++i)
                af[i] = *(const short8*)&Ab[(wvf * 64 + i * 16 + r16) * 64 + sa];
            #pragma unroll
            for (int j = 0; j < 2; ++j)
                bfr[j] = *(const short8*)&Bb[(wvg * 32 + j * 16 + r16) * 64 + sa];
            #pragma unroll
            for (int i = 0; i < 4; ++i)
                #pragma unroll
                for (int j = 0; j < 2; ++j)
                    acc[i][j] = MFMA16(af[i], bfr[j], acc[i][j]);
        }
        __builtin_amdgcn_s_setprio(0);
        asm volatile("s_waitcnt lgkmcnt(0)" ::: "memory");
        __builtin_amdgcn_s_barrier();
    }

    float* dst = plane ? CwI : CwR;
    const int nn2 = lane & 15, rq = (lane >> 4) * 4;
    #pragma unroll
    for (int i = 0; i < 4; ++i)
        #pragma unroll
        for (int j = 0; j < 2; ++j) {
            const int col = n0 + wvg * 32 + j * 16 + nn2;
            #pragma unroll
            for (int r = 0; r < 4; ++r) {
                const int f = f0 + wvf * 64 + i * 16 + rq + r;
                if (f < FF)
                    dst[((size_t)(b * FF + f)) * 512 + col] = acc[i][j][r];
            }
        }
}

// ---------------------------------------------------------------------------
// irfft8: Cw planes -> time domain, + bo, writes d_out (flag dtype).
// ---------------------------------------------------------------------------
__global__ __launch_bounds__(512) void irfft8(const float* __restrict__ CwR,
                                              const float* __restrict__ CwI,
                                              void* __restrict__ out,
                                              const float* __restrict__ bias_f,
                                              const int* __restrict__ flag)
{
    int b, dp;
    fft_decode(blockIdx.x, b, dp);
    const int d0 = dp * 8;
    __shared__ float2 sh[8192];
    __shared__ float2 twl[2048];
    const int tid = threadIdx.x;
    const int c = tid & 3, fb = tid >> 2;

    // hermitian construct
    for (int it = 0; it < 9; ++it) {
        const int f = fb + 128 * it;
        if (f < FF) {
            const size_t off = ((size_t)(b * FF + f)) * 512 + d0 + 2 * c;
            const float2 vr = *(const float2*)(CwR + off);
            const float2 vi = *(const float2*)(CwI + off);
            float c1x = vr.x, c1y = vi.x, c2x = vr.y, c2y = vi.y;
            if (f == 0 || f == 1024) { c1y = 0.f; c2y = 0.f; }
            sh[shx(f, c)] = make_float2(c1x - c2y, c1y + c2x);
            if (f >= 1 && f <= 1023)
                sh[shx(2048 - f, c)] = make_float2(c1x + c2y, c2x - c1y);
        }
    }
    fill_twl(twl, tid);
    __syncthreads();

    dif2048<true>(sh, twl, fb, c);

    // write + bo
    const float sc = 1.0f / 2048.0f;
    const float bo0 = bias_f[1536 + d0 + 2 * c];
    const float bo1 = bias_f[1536 + d0 + 2 * c + 1];
    const bool f32o = (*flag) != 0;
    const int lb = tid >> 2;
    #pragma unroll
    for (int it = 0; it < 16; ++it) {
        const int l  = lb * 16 + it;
        const int rl = __brev((unsigned)l) >> 21;
        const float2 z = sh[shx(rl, c)];
        const float o0 = z.x * sc + bo0;
        const float o1 = z.y * sc + bo1;
        const size_t off = ((size_t)(b * 2048 + l)) * 512 + d0 + 2 * c;
        if (f32o) {
            *(float2*)((float*)out + off) = make_float2(o0, o1);
        } else {
            __hip_bfloat162 h;
            h.x = f2b(o0); h.y = f2b(o1);
            *(__hip_bfloat162*)((bf16*)out + off) = h;
        }
    }
}

// ---------------------------------------------------------------------------
// launch — freq-domain pipeline, 9 dispatches.
// Regions:
//   A [0, 33.65MB):   attn (att out)
//   B [+37.75MB):     Xh (rfft_x out, panel layout) -> att16 | Csp
//   C [+17.04MB):     Asp -> CwR
//   D [+17.04MB):     Bsp -> CwI
//   E [+17.83MB):     Vct (8192 rows x GP=1088 x 2B = 17,825,792 exactly)
//   W [+4.2MB]:       WT, bias_f, flag
// ---------------------------------------------------------------------------
extern "C" void kernel_launch(void* const* d_in, const int* in_sizes, int n_in,
                              void* d_out, int out_size, void* d_ws, size_t ws_size,
                              hipStream_t stream)
{
    const void* x  = d_in[0];
    const void* Wq = d_in[1]; const void* bq = d_in[2];
    const void* Wk = d_in[3]; const void* bk = d_in[4];
    const void* Wv = d_in[5]; const void* bv = d_in[6];
    const void* Wo = d_in[7]; const void* bo = d_in[8];

    char* ws = (char*)d_ws;
    char* pA = ws;                          // 33,652,736
    char* pB = pA + 33652736;               // 37,748,736
    char* pC = pB + 37748736;               // 17,039,360
    char* pD = pC + 17039360;               // 17,039,360
    char* pE = pD + 17039360;               // 17,825,792
    char* pW = pE + 17825792;

    float*  attn = (float*)pA;
    bf16*   Xh   = (bf16*)pB;
    bf16*   att16= (bf16*)pB;                       // 8200*1088*2 = 17,843,200 B
    bf16*   Csp  = (bf16*)(pB + 17843200);          // + 18,874,368 <= region end
    bf16*   Asp  = (bf16*)pC;
    bf16*   Bsp  = (bf16*)pD;
    float*  CwR  = (float*)pC;
    float*  CwI  = (float*)pD;
    bf16*   Vct  = (bf16*)pE;
    bf16*   WT   = (bf16*)pW;
    float*  bias_f = (float*)(pW + 4194304);
    int*    flag = (int*)(pW + 4194304 + 8192);

    detect_dtype<<<1, 256, 0, stream>>>((const unsigned short*)x, flag);
    split_w_t<<<dim3(16, 16, 4), 256, 0, stream>>>(Wq, Wk, Wv, Wo, bq, bk, bv, bo,
                                                   WT, bias_f, flag);
    rfft_x<<<dim3(512), 512, 0, stream>>>(x, Xh, flag);
    proj_all<<<dim3(1728), 256, 0, stream>>>(Xh, WT, bias_f, Asp, Bsp, Vct);
    att_mfma<<<dim3(1224), 256, 0, stream>>>(Asp, Bsp, attn);
    softmax_rows<<<dim3(BB * FF), 256, 0, stream>>>(attn, att16);
    ctx_mfma<<<dim3(1152), 256, 0, stream>>>(att16, Vct, Csp);
    out_mfma_freq<<<dim3(144, 8), 256, 0, stream>>>(Csp, WT + 3 * 524288, CwR, CwI);
    irfft8<<<dim3(512), 512, 0, stream>>>(CwR, CwI, d_out, bias_f, flag);
}